// Round 6
// baseline (231.998 us; speedup 1.0000x reference)
//
#include <hip/hip_runtime.h>
#include <math.h>

#define Hdim 1024
#define VOC 32000
#define LSEQ 128
#define BSZ 64

typedef __attribute__((ext_vector_type(8))) short bf16x8;
typedef __attribute__((ext_vector_type(4))) float f32x4;

__device__ __forceinline__ float fast_tanhf(float x) {
    return 1.0f - 2.0f / (__expf(2.0f * x) + 1.0f);
}
__device__ __forceinline__ float sigmoidf(float x) {
    return 1.0f / (1.0f + __expf(-x));
}
__device__ __forceinline__ short f2bf(float f) {
    unsigned u = __float_as_uint(f);
    unsigned r = (u + 0x7fffu + ((u >> 16) & 1u)) >> 16;
    return (short)r;
}

// ---------------------------------------------------------------------------
// One-pass f32 -> bf16 conversion of enc, attn_W, hidden (grid-stride).
// ---------------------------------------------------------------------------
__global__ __launch_bounds__(256) void convert_bf16(
    const float* __restrict__ enc, const float* __restrict__ attnW,
    const float* __restrict__ hidden,
    short* __restrict__ enc_bf, short* __restrict__ attnW_bf,
    short* __restrict__ hidden_bf)
{
    const int NG_ENC = (LSEQ * BSZ * Hdim) / 8;   // 1048576
    const int NG_AW  = (Hdim * 2 * Hdim) / 8;     // 262144
    const int NG_H   = (BSZ * Hdim) / 8;          // 8192
    const int total = NG_ENC + NG_AW + NG_H;
    for (int g = blockIdx.x * 256 + threadIdx.x; g < total; g += gridDim.x * 256) {
        const float* src; short* dst; int idx;
        if (g < NG_ENC)              { src = enc;    dst = enc_bf;    idx = g; }
        else if (g < NG_ENC + NG_AW) { src = attnW;  dst = attnW_bf;  idx = g - NG_ENC; }
        else                         { src = hidden; dst = hidden_bf; idx = g - NG_ENC - NG_AW; }
        f32x4 a = *(const f32x4*)(src + (size_t)idx * 8);
        f32x4 b = *(const f32x4*)(src + (size_t)idx * 8 + 4);
        bf16x8 p;
        p[0] = f2bf(a[0]); p[1] = f2bf(a[1]); p[2] = f2bf(a[2]); p[3] = f2bf(a[3]);
        p[4] = f2bf(b[0]); p[5] = f2bf(b[1]); p[6] = f2bf(b[2]); p[7] = f2bf(b[3]);
        *(bf16x8*)(dst + (size_t)idx * 8) = p;
    }
}

// ---------------------------------------------------------------------------
// u partial GEMM: u4[s] = hidden_bf @ W2_bf^T  (split-K x4, bf16 operands)
// ---------------------------------------------------------------------------
__global__ __launch_bounds__(256) void ugemm(
    const short* __restrict__ A,    // hidden_bf [64,1024]
    const short* __restrict__ B,    // attnW_bf + Hdim, ld 2048
    float* __restrict__ C)          // [4][64,1024]
{
    __shared__ short As[64 * 72];
    __shared__ short Bs[128 * 72];

    const int t = threadIdx.x;
    const int lane = t & 63, wave = t >> 6;
    const int lr = lane & 15, kh = lane >> 4;
    const int n0 = blockIdx.x * 128;
    const int kstart = blockIdx.y * 256;
    float* Cp = C + (size_t)blockIdx.y * (BSZ * Hdim);

    const int ar = t >> 2, ac = (t & 3) * 16;
    const int br = t >> 1, bc = (t & 1) * 32;

    f32x4 acc[4][2] = {};

    for (int k0 = 0; k0 < 256; k0 += 64) {
        const int kg = kstart + k0;
        {
            const short* s = A + (size_t)ar * Hdim + kg + ac;
            *(bf16x8*)(As + ar * 72 + ac)     = *(const bf16x8*)(s);
            *(bf16x8*)(As + ar * 72 + ac + 8) = *(const bf16x8*)(s + 8);
        }
        {
            const short* s = B + (size_t)(n0 + br) * (2 * Hdim) + kg + bc;
            short* d = Bs + br * 72 + bc;
            *(bf16x8*)(d)      = *(const bf16x8*)(s);
            *(bf16x8*)(d + 8)  = *(const bf16x8*)(s + 8);
            *(bf16x8*)(d + 16) = *(const bf16x8*)(s + 16);
            *(bf16x8*)(d + 24) = *(const bf16x8*)(s + 24);
        }
        __syncthreads();
#pragma unroll
        for (int kk = 0; kk < 64; kk += 32) {
            bf16x8 af[4], bfr[2];
#pragma unroll
            for (int mi = 0; mi < 4; ++mi)
                af[mi] = *(const bf16x8*)(As + (mi * 16 + lr) * 72 + kk + kh * 8);
#pragma unroll
            for (int ni = 0; ni < 2; ++ni)
                bfr[ni] = *(const bf16x8*)(Bs + (wave * 32 + ni * 16 + lr) * 72 + kk + kh * 8);
#pragma unroll
            for (int mi = 0; mi < 4; ++mi)
#pragma unroll
                for (int ni = 0; ni < 2; ++ni)
                    acc[mi][ni] = __builtin_amdgcn_mfma_f32_16x16x32_bf16(
                        af[mi], bfr[ni], acc[mi][ni], 0, 0, 0);
        }
        __syncthreads();
    }

#pragma unroll
    for (int mi = 0; mi < 4; ++mi)
#pragma unroll
        for (int ni = 0; ni < 2; ++ni) {
            const int col = n0 + wave * 32 + ni * 16 + lr;
#pragma unroll
            for (int r = 0; r < 4; ++r) {
                const int row = mi * 16 + kh * 4 + r;
                Cp[(size_t)row * Hdim + col] = acc[mi][ni][r];
            }
        }
}

// ---------------------------------------------------------------------------
// Fused attention scores, 128x128 tile, 512 threads = 8 waves (2x4).
// ---------------------------------------------------------------------------
__global__ __launch_bounds__(512) void attn_scores_mfma(
    const short* __restrict__ enc_bf,   // [8192, 1024]
    const short* __restrict__ W1_bf,    // ld 2048, cols [0,1024)
    const float* __restrict__ u4,       // [4][64, 1024]
    const float* __restrict__ attnb,    // [1024]
    const float* __restrict__ vvec,     // [1024]
    float* __restrict__ scores_part)    // [8][8192]
{
    __shared__ short As[128 * 72];
    __shared__ short Bs[128 * 72];
    __shared__ float red[8][64];
    __shared__ float u_lds[64 * 128];

    const int t = threadIdx.x;
    const int lane = t & 63, wave = t >> 6;     // 8 waves
    const int wr = wave >> 2, wc = wave & 3;    // 2 x 4 wave grid
    const int lr = lane & 15, kh = lane >> 4;
    const int m0 = blockIdx.x * 128;
    const int n0 = blockIdx.y * 128;

    const int srow = t >> 2, scol = (t & 3) * 16;

    for (int i = t; i < 64 * 128; i += 512) {
        const int b = i >> 7, hl = i & 127;
        const size_t g = (size_t)b * Hdim + n0 + hl;
        u_lds[i] = u4[g] + u4[65536 + g] + u4[2 * 65536 + g] + u4[3 * 65536 + g]
                 + attnb[n0 + hl];
    }

    f32x4 acc[4][2] = {};

    for (int kg = 0; kg < Hdim; kg += 64) {
        {
            const short* s = enc_bf + (size_t)(m0 + srow) * Hdim + kg + scol;
            *(bf16x8*)(As + srow * 72 + scol)     = *(const bf16x8*)(s);
            *(bf16x8*)(As + srow * 72 + scol + 8) = *(const bf16x8*)(s + 8);
        }
        {
            const short* s = W1_bf + (size_t)(n0 + srow) * (2 * Hdim) + kg + scol;
            *(bf16x8*)(Bs + srow * 72 + scol)     = *(const bf16x8*)(s);
            *(bf16x8*)(Bs + srow * 72 + scol + 8) = *(const bf16x8*)(s + 8);
        }
        __syncthreads();
#pragma unroll
        for (int kk = 0; kk < 64; kk += 32) {
            bf16x8 af[4], bfr[2];
#pragma unroll
            for (int mi = 0; mi < 4; ++mi)
                af[mi] = *(const bf16x8*)(As + (wr * 64 + mi * 16 + lr) * 72 + kk + kh * 8);
#pragma unroll
            for (int ni = 0; ni < 2; ++ni)
                bfr[ni] = *(const bf16x8*)(Bs + (wc * 32 + ni * 16 + lr) * 72 + kk + kh * 8);
#pragma unroll
            for (int mi = 0; mi < 4; ++mi)
#pragma unroll
                for (int ni = 0; ni < 2; ++ni)
                    acc[mi][ni] = __builtin_amdgcn_mfma_f32_16x16x32_bf16(
                        af[mi], bfr[ni], acc[mi][ni], 0, 0, 0);
        }
        __syncthreads();
    }

    float sv[16];
#pragma unroll
    for (int mi = 0; mi < 4; ++mi)
#pragma unroll
        for (int r = 0; r < 4; ++r) {
            const int lrow = mi * 16 + kh * 4 + r;
            const int b = lrow;
            float s = 0.0f;
#pragma unroll
            for (int ni = 0; ni < 2; ++ni) {
                const int hl = wc * 32 + ni * 16 + lr;
                const float e = fast_tanhf(acc[mi][ni][r] + u_lds[b * 128 + hl]);
                s += e * vvec[n0 + hl];
            }
            sv[mi * 4 + r] = s;
        }
#pragma unroll
    for (int i = 0; i < 16; ++i) {
#pragma unroll
        for (int d = 1; d < 16; d <<= 1)
            sv[i] += __shfl_xor(sv[i], d, 64);
    }
    if (lr == 0) {
#pragma unroll
        for (int mi = 0; mi < 4; ++mi)
#pragma unroll
            for (int r = 0; r < 4; ++r)
                red[wave][mi * 16 + kh * 4 + r] = sv[mi * 4 + r];
    }
    __syncthreads();
    if (t < 128) {
        const int wrr = t >> 6, lrow = t & 63;
        scores_part[(size_t)blockIdx.y * (LSEQ * BSZ) + m0 + t] =
            red[wrr * 4 + 0][lrow] + red[wrr * 4 + 1][lrow] +
            red[wrr * 4 + 2][lrow] + red[wrr * 4 + 3][lrow];
    }
}

// ---------------------------------------------------------------------------
// Fused softmax + weighted context + embedding. grid(64 b, 4 hg), 128 thr.
// Each block: full softmax (cheap, redundant x4) + 256-col slice of weighted.
// ---------------------------------------------------------------------------
__global__ __launch_bounds__(128) void softmax_weighted(
    const float* __restrict__ sp,       // [8][8192]
    const short* __restrict__ enc_bf,   // [8192, 1024]
    const int* __restrict__ ids,
    const float* __restrict__ emb,
    float* __restrict__ attn_out,       // [B, L]
    short* __restrict__ x_bf,           // [64, 2048]
    short* __restrict__ oc_bf)          // [64, 3072]
{
    const int b = blockIdx.x, hg = blockIdx.y, t = threadIdx.x;
    __shared__ float aw[LSEQ];
    __shared__ float red[LSEQ];

    // embedding gather (hg==0 only): thread t covers cols t*8..t*8+7
    if (hg == 0) {
        const int id = ids[b];
        const int h = t * 8;
        f32x4 e0 = *(const f32x4*)(emb + (size_t)id * Hdim + h);
        f32x4 e1 = *(const f32x4*)(emb + (size_t)id * Hdim + h + 4);
        bf16x8 p;
        p[0] = f2bf(e0[0]); p[1] = f2bf(e0[1]); p[2] = f2bf(e0[2]); p[3] = f2bf(e0[3]);
        p[4] = f2bf(e1[0]); p[5] = f2bf(e1[1]); p[6] = f2bf(e1[2]); p[7] = f2bf(e1[3]);
        *(bf16x8*)(x_bf + (size_t)b * 2048 + h) = p;
        *(bf16x8*)(oc_bf + (size_t)b * 3072 + 2048 + h) = p;
    }

    // softmax over L=128, one thread per l
    float s = 0.0f;
#pragma unroll
    for (int g = 0; g < 8; ++g) s += sp[g * (LSEQ * BSZ) + t * 64 + b];
    red[t] = s;
    __syncthreads();
    for (int off = 64; off > 0; off >>= 1) {
        if (t < off) red[t] = fmaxf(red[t], red[t + off]);
        __syncthreads();
    }
    const float mx = red[0];
    __syncthreads();
    const float e = __expf(s - mx);
    red[t] = e;
    __syncthreads();
    for (int off = 64; off > 0; off >>= 1) {
        if (t < off) red[t] += red[t + off];
        __syncthreads();
    }
    const float p = e / red[0];
    aw[t] = p;
    if (hg == 0) attn_out[(size_t)b * LSEQ + t] = p;
    __syncthreads();

    // weighted context for this block's 256 cols: thread t -> col pair
    const int h = hg * 256 + t * 2;
    float a0 = 0.0f, a1 = 0.0f;
#pragma unroll 8
    for (int l = 0; l < LSEQ; ++l) {
        const unsigned w = *(const unsigned*)(enc_bf + ((size_t)l * BSZ + b) * Hdim + h);
        const float pw = aw[l];
        a0 = fmaf(pw, __uint_as_float(w << 16), a0);
        a1 = fmaf(pw, __uint_as_float(w & 0xffff0000u), a1);
    }
    const unsigned packed = (unsigned)(unsigned short)f2bf(a0)
                          | ((unsigned)(unsigned short)f2bf(a1) << 16);
    *(unsigned*)(x_bf + (size_t)b * 2048 + 1024 + h) = packed;
    *(unsigned*)(oc_bf + (size_t)b * 3072 + 1024 + h) = packed;
}

// ---------------------------------------------------------------------------
// Barrier-free streaming skinny GEMM body: C = A_bf16[64,K] @ B_f32[N,K]^T
// No LDS: A fragments loaded direct from L2-resident A; B fragments are
// 32B contiguous f32 loads converted in-register. BN=64 per block
// (4 waves x 16 cols), unroll-4 for >=64KB/CU of in-flight B loads.
// ---------------------------------------------------------------------------
__device__ __forceinline__ void stream_body(
    const short* __restrict__ A, int lda,
    const float* __restrict__ B, int ldb,
    const float* __restrict__ bias,
    float* __restrict__ C, int ldc,
    int n0, int kstart, int klen)
{
    const int t = threadIdx.x;
    const int lane = t & 63, wave = t >> 6;
    const int lr = lane & 15, kh = lane >> 4;

    const float* Brow = B + (size_t)(n0 + wave * 16 + lr) * ldb + kh * 8 + kstart;
    const short* Ab   = A + (size_t)lr * lda + kh * 8 + kstart;

    f32x4 acc[4] = {};

#pragma unroll 4
    for (int kg = 0; kg < klen; kg += 32) {
        f32x4 b0 = *(const f32x4*)(Brow + kg);
        f32x4 b1 = *(const f32x4*)(Brow + kg + 4);
        bf16x8 bfr;
        bfr[0] = f2bf(b0[0]); bfr[1] = f2bf(b0[1]); bfr[2] = f2bf(b0[2]); bfr[3] = f2bf(b0[3]);
        bfr[4] = f2bf(b1[0]); bfr[5] = f2bf(b1[1]); bfr[6] = f2bf(b1[2]); bfr[7] = f2bf(b1[3]);
#pragma unroll
        for (int mi = 0; mi < 4; ++mi) {
            bf16x8 af = *(const bf16x8*)(Ab + (size_t)mi * 16 * lda + kg);
            acc[mi] = __builtin_amdgcn_mfma_f32_16x16x32_bf16(af, bfr, acc[mi], 0, 0, 0);
        }
    }

    const int col = n0 + wave * 16 + lr;
    const float bb = bias ? bias[col] : 0.0f;
#pragma unroll
    for (int mi = 0; mi < 4; ++mi)
#pragma unroll
        for (int r = 0; r < 4; ++r)
            C[(size_t)(mi * 16 + kh * 4 + r) * ldc + col] = acc[mi][r] + bb;
}

// Output projection: logits = oc_bf @ out_W^T + out_b.  grid(500), 256 thr.
__global__ __launch_bounds__(256) void outproj_stream(
    const short* __restrict__ A, const float* __restrict__ B,
    const float* __restrict__ bias, float* __restrict__ logits)
{
    stream_body(A, 3 * Hdim, B, 3 * Hdim, bias, logits, VOC,
                blockIdx.x * 64, 0, 3 * Hdim);
}

// Merged GRU gate GEMMs, split-K x4 partials. grid(96, 4), 256 thr.
__global__ __launch_bounds__(256) void gxgh_stream(
    const short* __restrict__ x_bf, const float* __restrict__ w_ih,
    const short* __restrict__ hidden_bf, const float* __restrict__ w_hh,
    float* __restrict__ gx4, float* __restrict__ gh4)
{
    const size_t P = (size_t)BSZ * 3 * Hdim;
    if (blockIdx.x < 48)
        stream_body(x_bf, 2 * Hdim, w_ih, 2 * Hdim, nullptr,
                    gx4 + blockIdx.y * P, 3 * Hdim,
                    blockIdx.x * 64, blockIdx.y * 512, 512);
    else
        stream_body(hidden_bf, Hdim, w_hh, Hdim, nullptr,
                    gh4 + blockIdx.y * P, 3 * Hdim,
                    (blockIdx.x - 48) * 64, blockIdx.y * 256, 256);
}

// ---------------------------------------------------------------------------
// GRU elementwise; sums 4 split-K partials + biases; bf16 out_cat write.
// ---------------------------------------------------------------------------
__global__ __launch_bounds__(256) void gru_kernel(
    const float* __restrict__ gx4, const float* __restrict__ gh4,
    const float* __restrict__ b_ih, const float* __restrict__ b_hh,
    const float* __restrict__ h0,
    float* __restrict__ hnew_out, short* __restrict__ oc_bf)
{
    const int idx = blockIdx.x * 256 + threadIdx.x;
    const int b = idx >> 10, h = idx & 1023;
    const size_t g3 = (size_t)b * (3 * Hdim);
    const size_t P = (size_t)BSZ * 3 * Hdim;
    float xr = b_ih[h], xz = b_ih[Hdim + h], xn = b_ih[2 * Hdim + h];
    float hr = b_hh[h], hz = b_hh[Hdim + h], hn = b_hh[2 * Hdim + h];
#pragma unroll
    for (int s = 0; s < 4; ++s) {
        xr += gx4[s * P + g3 + h];
        xz += gx4[s * P + g3 + Hdim + h];
        xn += gx4[s * P + g3 + 2 * Hdim + h];
        hr += gh4[s * P + g3 + h];
        hz += gh4[s * P + g3 + Hdim + h];
        hn += gh4[s * P + g3 + 2 * Hdim + h];
    }
    const float r = sigmoidf(xr + hr);
    const float z = sigmoidf(xz + hz);
    const float n = fast_tanhf(xn + r * hn);
    const float hv = (1.0f - z) * n + z * h0[(size_t)b * Hdim + h];
    hnew_out[(size_t)b * Hdim + h] = hv;
    oc_bf[g3 + h] = f2bf(hv);
}

// ---------------------------------------------------------------------------
extern "C" void kernel_launch(void* const* d_in, const int* in_sizes, int n_in,
                              void* d_out, int out_size, void* d_ws, size_t ws_size,
                              hipStream_t stream)
{
    const int*   ids    = (const int*)d_in[0];
    const float* hidden = (const float*)d_in[1];
    const float* enc    = (const float*)d_in[2];
    const float* emb    = (const float*)d_in[3];
    const float* attnW  = (const float*)d_in[4];
    const float* attnb  = (const float*)d_in[5];
    const float* vvec   = (const float*)d_in[6];
    const float* w_ih   = (const float*)d_in[7];
    const float* w_hh   = (const float*)d_in[8];
    const float* b_ih   = (const float*)d_in[9];
    const float* b_hh   = (const float*)d_in[10];
    const float* out_W  = (const float*)d_in[11];
    const float* out_b  = (const float*)d_in[12];

    float* out        = (float*)d_out;
    float* out_logits = out;
    float* out_hnew   = out + (size_t)BSZ * VOC;
    float* out_attn   = out_hnew + (size_t)BSZ * Hdim;

    float* ws = (float*)d_ws;
    short* enc_bf    = (short*)ws;
    short* attnW_bf  = (short*)(ws + 4194304);
    short* hidden_bf = (short*)(ws + 5242880);
    float* ws_u4  = ws + 5275648;
    float* ws_sp  = ws_u4 + 262144;
    short* x_bf   = (short*)(ws_sp + 65536);
    short* oc_bf  = (short*)(ws_sp + 131072);
    float* ws_gx4 = ws_sp + 229376;
    float* ws_gh4 = ws_gx4 + 786432;

    // 1. f32 -> bf16 one-pass conversion
    convert_bf16<<<dim3(1024), 256, 0, stream>>>(
        enc, attnW, hidden, enc_bf, attnW_bf, hidden_bf);

    // 2. u partials: hidden_bf @ W2_bf^T (split-K x4, 32 blocks)
    ugemm<<<dim3(Hdim / 128, 4), 256, 0, stream>>>(
        hidden_bf, attnW_bf + Hdim, ws_u4);

    // 3. fused energy GEMM + u-combine + tanh + v-reduction
    attn_scores_mfma<<<dim3(LSEQ / 2, 8), 512, 0, stream>>>(
        enc_bf, attnW_bf, ws_u4, attnb, vvec, ws_sp);

    // 4. softmax + weighted context + embedding (256 blocks)
    softmax_weighted<<<dim3(BSZ, 4), 128, 0, stream>>>(
        ws_sp, enc_bf, ids, emb, out_attn, x_bf, oc_bf);

    // 5. merged GRU gate GEMMs, barrier-free streaming (384 blocks)
    gxgh_stream<<<dim3(96, 4), 256, 0, stream>>>(
        x_bf, w_ih, hidden_bf, w_hh, ws_gx4, ws_gh4);

    // 6. GRU elementwise
    gru_kernel<<<dim3(BSZ * Hdim / 256), 256, 0, stream>>>(
        ws_gx4, ws_gh4, b_ih, b_hh, hidden, out_hnew, oc_bf);

    // 7. output projection, barrier-free streaming (500 blocks)
    outproj_stream<<<dim3(VOC / 64), 256, 0, stream>>>(
        oc_bf, out_W, out_b, out_logits);
}

// Round 7
// 185.852 us; speedup vs baseline: 1.2483x; 1.2483x over previous
//
#include <hip/hip_runtime.h>
#include <math.h>

#define Hdim 1024
#define VOC 32000
#define LSEQ 128
#define BSZ 64

typedef __attribute__((ext_vector_type(8))) short bf16x8;
typedef __attribute__((ext_vector_type(4))) float f32x4;

__device__ __forceinline__ float fast_tanhf(float x) {
    return 1.0f - 2.0f / (__expf(2.0f * x) + 1.0f);
}
__device__ __forceinline__ float sigmoidf(float x) {
    return 1.0f / (1.0f + __expf(-x));
}
__device__ __forceinline__ short f2bf(float f) {
    unsigned u = __float_as_uint(f);
    unsigned r = (u + 0x7fffu + ((u >> 16) & 1u)) >> 16;
    return (short)r;
}

// async global->LDS, 16 bytes per lane (dest must be linear: base + lane*16)
__device__ __forceinline__ void gl_lds16(const short* g, short* l) {
    __builtin_amdgcn_global_load_lds(
        (const __attribute__((address_space(1))) unsigned*)g,
        (__attribute__((address_space(3))) unsigned*)l, 16, 0, 0);
}

// 16 consecutive f32 -> 16 bf16 at dst (2x 16B stores)
__device__ __forceinline__ void stage16(const float* __restrict__ src, short* dst) {
    f32x4 v0 = *(const f32x4*)(src);
    f32x4 v1 = *(const f32x4*)(src + 4);
    f32x4 v2 = *(const f32x4*)(src + 8);
    f32x4 v3 = *(const f32x4*)(src + 12);
    bf16x8 p0, p1;
    p0[0] = f2bf(v0[0]); p0[1] = f2bf(v0[1]); p0[2] = f2bf(v0[2]); p0[3] = f2bf(v0[3]);
    p0[4] = f2bf(v1[0]); p0[5] = f2bf(v1[1]); p0[6] = f2bf(v1[2]); p0[7] = f2bf(v1[3]);
    p1[0] = f2bf(v2[0]); p1[1] = f2bf(v2[1]); p1[2] = f2bf(v2[2]); p1[3] = f2bf(v2[3]);
    p1[4] = f2bf(v3[0]); p1[5] = f2bf(v3[1]); p1[6] = f2bf(v3[2]); p1[7] = f2bf(v3[3]);
    *(bf16x8*)(dst) = p0;
    *(bf16x8*)(dst + 8) = p1;
}

// ---------------------------------------------------------------------------
// One-pass f32 -> bf16 conversion of enc, attn_W, hidden (grid-stride).
// ---------------------------------------------------------------------------
__global__ __launch_bounds__(256) void convert_bf16(
    const float* __restrict__ enc, const float* __restrict__ attnW,
    const float* __restrict__ hidden,
    short* __restrict__ enc_bf, short* __restrict__ attnW_bf,
    short* __restrict__ hidden_bf)
{
    const int NG_ENC = (LSEQ * BSZ * Hdim) / 8;   // 1048576
    const int NG_AW  = (Hdim * 2 * Hdim) / 8;     // 262144
    const int NG_H   = (BSZ * Hdim) / 8;          // 8192
    const int total = NG_ENC + NG_AW + NG_H;
    for (int g = blockIdx.x * 256 + threadIdx.x; g < total; g += gridDim.x * 256) {
        const float* src; short* dst; int idx;
        if (g < NG_ENC)              { src = enc;    dst = enc_bf;    idx = g; }
        else if (g < NG_ENC + NG_AW) { src = attnW;  dst = attnW_bf;  idx = g - NG_ENC; }
        else                         { src = hidden; dst = hidden_bf; idx = g - NG_ENC - NG_AW; }
        f32x4 a = *(const f32x4*)(src + (size_t)idx * 8);
        f32x4 b = *(const f32x4*)(src + (size_t)idx * 8 + 4);
        bf16x8 p;
        p[0] = f2bf(a[0]); p[1] = f2bf(a[1]); p[2] = f2bf(a[2]); p[3] = f2bf(a[3]);
        p[4] = f2bf(b[0]); p[5] = f2bf(b[1]); p[6] = f2bf(b[2]); p[7] = f2bf(b[3]);
        *(bf16x8*)(dst + (size_t)idx * 8) = p;
    }
}

// ---------------------------------------------------------------------------
// u partial GEMM: u4[s] = hidden_bf @ W2_bf^T  (split-K x4, bf16 operands)
// ---------------------------------------------------------------------------
__global__ __launch_bounds__(256) void ugemm(
    const short* __restrict__ A,    // hidden_bf [64,1024]
    const short* __restrict__ B,    // attnW_bf + Hdim, ld 2048
    float* __restrict__ C)          // [4][64,1024]
{
    __shared__ short As[64 * 72];
    __shared__ short Bs[128 * 72];

    const int t = threadIdx.x;
    const int lane = t & 63, wave = t >> 6;
    const int lr = lane & 15, kh = lane >> 4;
    const int n0 = blockIdx.x * 128;
    const int kstart = blockIdx.y * 256;
    float* Cp = C + (size_t)blockIdx.y * (BSZ * Hdim);

    const int ar = t >> 2, ac = (t & 3) * 16;
    const int br = t >> 1, bc = (t & 1) * 32;

    f32x4 acc[4][2] = {};

    for (int k0 = 0; k0 < 256; k0 += 64) {
        const int kg = kstart + k0;
        {
            const short* s = A + (size_t)ar * Hdim + kg + ac;
            *(bf16x8*)(As + ar * 72 + ac)     = *(const bf16x8*)(s);
            *(bf16x8*)(As + ar * 72 + ac + 8) = *(const bf16x8*)(s + 8);
        }
        {
            const short* s = B + (size_t)(n0 + br) * (2 * Hdim) + kg + bc;
            short* d = Bs + br * 72 + bc;
            *(bf16x8*)(d)      = *(const bf16x8*)(s);
            *(bf16x8*)(d + 8)  = *(const bf16x8*)(s + 8);
            *(bf16x8*)(d + 16) = *(const bf16x8*)(s + 16);
            *(bf16x8*)(d + 24) = *(const bf16x8*)(s + 24);
        }
        __syncthreads();
#pragma unroll
        for (int kk = 0; kk < 64; kk += 32) {
            bf16x8 af[4], bfr[2];
#pragma unroll
            for (int mi = 0; mi < 4; ++mi)
                af[mi] = *(const bf16x8*)(As + (mi * 16 + lr) * 72 + kk + kh * 8);
#pragma unroll
            for (int ni = 0; ni < 2; ++ni)
                bfr[ni] = *(const bf16x8*)(Bs + (wave * 32 + ni * 16 + lr) * 72 + kk + kh * 8);
#pragma unroll
            for (int mi = 0; mi < 4; ++mi)
#pragma unroll
                for (int ni = 0; ni < 2; ++ni)
                    acc[mi][ni] = __builtin_amdgcn_mfma_f32_16x16x32_bf16(
                        af[mi], bfr[ni], acc[mi][ni], 0, 0, 0);
        }
        __syncthreads();
    }

#pragma unroll
    for (int mi = 0; mi < 4; ++mi)
#pragma unroll
        for (int ni = 0; ni < 2; ++ni) {
            const int col = n0 + wave * 32 + ni * 16 + lr;
#pragma unroll
            for (int r = 0; r < 4; ++r) {
                const int row = mi * 16 + kh * 4 + r;
                Cp[(size_t)row * Hdim + col] = acc[mi][ni][r];
            }
        }
}

// ---------------------------------------------------------------------------
// Fused attention scores, 128x128 tile, 512 threads = 8 waves (2x4).
// Staging via global_load_lds (m97 pattern): linear [128][64] bf16 tiles.
// ---------------------------------------------------------------------------
__global__ __launch_bounds__(512) void attn_scores_mfma(
    const short* __restrict__ enc_bf,   // [8192, 1024]
    const short* __restrict__ W1_bf,    // ld 2048, cols [0,1024)
    const float* __restrict__ u4,       // [4][64, 1024]
    const float* __restrict__ attnb,    // [1024]
    const float* __restrict__ vvec,     // [1024]
    float* __restrict__ scores_part)    // [8][8192]
{
    __shared__ short As[128 * 64];      // linear: row*64 + k
    __shared__ short Bs[128 * 64];
    __shared__ float red[8][64];
    __shared__ float u_lds[64 * 128];

    const int t = threadIdx.x;
    const int lane = t & 63, wave = t >> 6;     // 8 waves
    const int wr = wave >> 2, wc = wave & 3;    // 2 x 4 wave grid
    const int lr = lane & 15, kh = lane >> 4;
    const int m0 = blockIdx.x * 128;
    const int n0 = blockIdx.y * 128;

    // gload_lds geometry: byte offset o covers row o>>7, short-col (o&127)>>1.
    const int o1 = t * 16;            // 0..8191
    const int o2 = 8192 + t * 16;     // 8192..16383
    const int r1 = o1 >> 7, c1 = (o1 & 127) >> 1;
    const int r2 = o2 >> 7, c2 = (o2 & 127) >> 1;

    // u-sum table for this block's 128 h-cols (covered by first sync)
    for (int i = t; i < 64 * 128; i += 512) {
        const int b = i >> 7, hl = i & 127;
        const size_t g = (size_t)b * Hdim + n0 + hl;
        u_lds[i] = u4[g] + u4[65536 + g] + u4[2 * 65536 + g] + u4[3 * 65536 + g]
                 + attnb[n0 + hl];
    }

    f32x4 acc[4][2] = {};

    for (int kg = 0; kg < Hdim; kg += 64) {
        gl_lds16(enc_bf + (size_t)(m0 + r1) * Hdim + kg + c1, As + (o1 >> 1));
        gl_lds16(enc_bf + (size_t)(m0 + r2) * Hdim + kg + c2, As + (o2 >> 1));
        gl_lds16(W1_bf + (size_t)(n0 + r1) * (2 * Hdim) + kg + c1, Bs + (o1 >> 1));
        gl_lds16(W1_bf + (size_t)(n0 + r2) * (2 * Hdim) + kg + c2, Bs + (o2 >> 1));
        __syncthreads();
#pragma unroll
        for (int kk = 0; kk < 64; kk += 32) {
            bf16x8 af[4], bfr[2];
#pragma unroll
            for (int mi = 0; mi < 4; ++mi)
                af[mi] = *(const bf16x8*)(As + (wr * 64 + mi * 16 + lr) * 64 + kk + kh * 8);
#pragma unroll
            for (int ni = 0; ni < 2; ++ni)
                bfr[ni] = *(const bf16x8*)(Bs + (wc * 32 + ni * 16 + lr) * 64 + kk + kh * 8);
#pragma unroll
            for (int mi = 0; mi < 4; ++mi)
#pragma unroll
                for (int ni = 0; ni < 2; ++ni)
                    acc[mi][ni] = __builtin_amdgcn_mfma_f32_16x16x32_bf16(
                        af[mi], bfr[ni], acc[mi][ni], 0, 0, 0);
        }
        __syncthreads();
    }

    float sv[16];
#pragma unroll
    for (int mi = 0; mi < 4; ++mi)
#pragma unroll
        for (int r = 0; r < 4; ++r) {
            const int lrow = mi * 16 + kh * 4 + r;
            const int b = lrow;
            float s = 0.0f;
#pragma unroll
            for (int ni = 0; ni < 2; ++ni) {
                const int hl = wc * 32 + ni * 16 + lr;
                const float e = fast_tanhf(acc[mi][ni][r] + u_lds[b * 128 + hl]);
                s += e * vvec[n0 + hl];
            }
            sv[mi * 4 + r] = s;
        }
#pragma unroll
    for (int i = 0; i < 16; ++i) {
#pragma unroll
        for (int d = 1; d < 16; d <<= 1)
            sv[i] += __shfl_xor(sv[i], d, 64);
    }
    if (lr == 0) {
#pragma unroll
        for (int mi = 0; mi < 4; ++mi)
#pragma unroll
            for (int r = 0; r < 4; ++r)
                red[wave][mi * 16 + kh * 4 + r] = sv[mi * 4 + r];
    }
    __syncthreads();
    if (t < 128) {
        const int wrr = t >> 6, lrow = t & 63;
        scores_part[(size_t)blockIdx.y * (LSEQ * BSZ) + m0 + t] =
            red[wrr * 4 + 0][lrow] + red[wrr * 4 + 1][lrow] +
            red[wrr * 4 + 2][lrow] + red[wrr * 4 + 3][lrow];
    }
}

// ---------------------------------------------------------------------------
// Fused softmax + weighted context + embedding. grid(64 b, 4 hg), 128 thr.
// ---------------------------------------------------------------------------
__global__ __launch_bounds__(128) void softmax_weighted(
    const float* __restrict__ sp,       // [8][8192]
    const short* __restrict__ enc_bf,   // [8192, 1024]
    const int* __restrict__ ids,
    const float* __restrict__ emb,
    float* __restrict__ attn_out,       // [B, L]
    short* __restrict__ x_bf,           // [64, 2048]
    short* __restrict__ oc_bf)          // [64, 3072]
{
    const int b = blockIdx.x, hg = blockIdx.y, t = threadIdx.x;
    __shared__ float aw[LSEQ];
    __shared__ float red[LSEQ];

    if (hg == 0) {
        const int id = ids[b];
        const int h = t * 8;
        f32x4 e0 = *(const f32x4*)(emb + (size_t)id * Hdim + h);
        f32x4 e1 = *(const f32x4*)(emb + (size_t)id * Hdim + h + 4);
        bf16x8 p;
        p[0] = f2bf(e0[0]); p[1] = f2bf(e0[1]); p[2] = f2bf(e0[2]); p[3] = f2bf(e0[3]);
        p[4] = f2bf(e1[0]); p[5] = f2bf(e1[1]); p[6] = f2bf(e1[2]); p[7] = f2bf(e1[3]);
        *(bf16x8*)(x_bf + (size_t)b * 2048 + h) = p;
        *(bf16x8*)(oc_bf + (size_t)b * 3072 + 2048 + h) = p;
    }

    float s = 0.0f;
#pragma unroll
    for (int g = 0; g < 8; ++g) s += sp[g * (LSEQ * BSZ) + t * 64 + b];
    red[t] = s;
    __syncthreads();
    for (int off = 64; off > 0; off >>= 1) {
        if (t < off) red[t] = fmaxf(red[t], red[t + off]);
        __syncthreads();
    }
    const float mx = red[0];
    __syncthreads();
    const float e = __expf(s - mx);
    red[t] = e;
    __syncthreads();
    for (int off = 64; off > 0; off >>= 1) {
        if (t < off) red[t] += red[t + off];
        __syncthreads();
    }
    const float p = e / red[0];
    aw[t] = p;
    if (hg == 0) attn_out[(size_t)b * LSEQ + t] = p;
    __syncthreads();

    const int h = hg * 256 + t * 2;
    float a0 = 0.0f, a1 = 0.0f;
#pragma unroll 8
    for (int l = 0; l < LSEQ; ++l) {
        const unsigned w = *(const unsigned*)(enc_bf + ((size_t)l * BSZ + b) * Hdim + h);
        const float pw = aw[l];
        a0 = fmaf(pw, __uint_as_float(w << 16), a0);
        a1 = fmaf(pw, __uint_as_float(w & 0xffff0000u), a1);
    }
    const unsigned packed = (unsigned)(unsigned short)f2bf(a0)
                          | ((unsigned)(unsigned short)f2bf(a1) << 16);
    *(unsigned*)(x_bf + (size_t)b * 2048 + 1024 + h) = packed;
    *(unsigned*)(oc_bf + (size_t)b * 3072 + 1024 + h) = packed;
}

// ---------------------------------------------------------------------------
// Merged GRU gate GEMMs (R5 LDS-staged form): blockIdx.x<24 -> gx, else gh.
// ---------------------------------------------------------------------------
__global__ __launch_bounds__(256) void gxgh_gemm(
    const short* __restrict__ x_bf, const float* __restrict__ w_ih,
    const short* __restrict__ hidden_bf, const float* __restrict__ w_hh,
    float* __restrict__ gx4, float* __restrict__ gh4)
{
    __shared__ short As[64 * 72];
    __shared__ short Bs[128 * 72];

    const int t = threadIdx.x;
    const int lane = t & 63, wave = t >> 6;
    const int lr = lane & 15, kh = lane >> 4;

    const short* A; const float* B; float* C; int lda, klen, n0;
    if (blockIdx.x < 24) {
        A = x_bf; B = w_ih; C = gx4; lda = 2048; klen = 512; n0 = blockIdx.x * 128;
    } else {
        A = hidden_bf; B = w_hh; C = gh4; lda = 1024; klen = 256; n0 = (blockIdx.x - 24) * 128;
    }
    const int kstart = blockIdx.y * klen;
    float* Cp = C + (size_t)blockIdx.y * (BSZ * 3 * Hdim);

    const int ar = t >> 2, ac = (t & 3) * 16;
    const int br = t >> 1, bc = (t & 1) * 32;

    f32x4 acc[4][2] = {};

    for (int k0 = 0; k0 < klen; k0 += 64) {
        const int kg = kstart + k0;
        {
            const short* s = A + (size_t)ar * lda + kg + ac;
            *(bf16x8*)(As + ar * 72 + ac)     = *(const bf16x8*)(s);
            *(bf16x8*)(As + ar * 72 + ac + 8) = *(const bf16x8*)(s + 8);
        }
        {
            const float* s = B + (size_t)(n0 + br) * lda + kg + bc;
            stage16(s,      Bs + br * 72 + bc);
            stage16(s + 16, Bs + br * 72 + bc + 16);
        }
        __syncthreads();
#pragma unroll
        for (int kk = 0; kk < 64; kk += 32) {
            bf16x8 af[4], bfr[2];
#pragma unroll
            for (int mi = 0; mi < 4; ++mi)
                af[mi] = *(const bf16x8*)(As + (mi * 16 + lr) * 72 + kk + kh * 8);
#pragma unroll
            for (int ni = 0; ni < 2; ++ni)
                bfr[ni] = *(const bf16x8*)(Bs + (wave * 32 + ni * 16 + lr) * 72 + kk + kh * 8);
#pragma unroll
            for (int mi = 0; mi < 4; ++mi)
#pragma unroll
                for (int ni = 0; ni < 2; ++ni)
                    acc[mi][ni] = __builtin_amdgcn_mfma_f32_16x16x32_bf16(
                        af[mi], bfr[ni], acc[mi][ni], 0, 0, 0);
        }
        __syncthreads();
    }

#pragma unroll
    for (int mi = 0; mi < 4; ++mi)
#pragma unroll
        for (int ni = 0; ni < 2; ++ni) {
            const int col = n0 + wave * 32 + ni * 16 + lr;
#pragma unroll
            for (int r = 0; r < 4; ++r) {
                const int row = mi * 16 + kh * 4 + r;
                Cp[(size_t)row * (3 * Hdim) + col] = acc[mi][ni][r];
            }
        }
}

// ---------------------------------------------------------------------------
// GRU elementwise; sums 4 split-K partials + biases; bf16 out_cat write.
// ---------------------------------------------------------------------------
__global__ __launch_bounds__(256) void gru_kernel(
    const float* __restrict__ gx4, const float* __restrict__ gh4,
    const float* __restrict__ b_ih, const float* __restrict__ b_hh,
    const float* __restrict__ h0,
    float* __restrict__ hnew_out, short* __restrict__ oc_bf)
{
    const int idx = blockIdx.x * 256 + threadIdx.x;
    const int b = idx >> 10, h = idx & 1023;
    const size_t g3 = (size_t)b * (3 * Hdim);
    const size_t P = (size_t)BSZ * 3 * Hdim;
    float xr = b_ih[h], xz = b_ih[Hdim + h], xn = b_ih[2 * Hdim + h];
    float hr = b_hh[h], hz = b_hh[Hdim + h], hn = b_hh[2 * Hdim + h];
#pragma unroll
    for (int s = 0; s < 4; ++s) {
        xr += gx4[s * P + g3 + h];
        xz += gx4[s * P + g3 + Hdim + h];
        xn += gx4[s * P + g3 + 2 * Hdim + h];
        hr += gh4[s * P + g3 + h];
        hz += gh4[s * P + g3 + Hdim + h];
        hn += gh4[s * P + g3 + 2 * Hdim + h];
    }
    const float r = sigmoidf(xr + hr);
    const float z = sigmoidf(xz + hz);
    const float n = fast_tanhf(xn + r * hn);
    const float hv = (1.0f - z) * n + z * h0[(size_t)b * Hdim + h];
    hnew_out[(size_t)b * Hdim + h] = hv;
    oc_bf[g3 + h] = f2bf(hv);
}

// ---------------------------------------------------------------------------
// Output projection, direct write, with register-prefetch double buffering:
// issue next tile's global loads right after the fill barrier so HBM stays
// busy during compute + drain. BN=64, 256 thr, grid 500, full K=3072.
// ---------------------------------------------------------------------------
__global__ __launch_bounds__(256) void outproj_direct(
    const short* __restrict__ A,    // [64, 3072] bf16
    const float* __restrict__ B,    // [32000, 3072] f32
    const float* __restrict__ bias, // [32000]
    float* __restrict__ logits)     // [64, 32000]
{
    __shared__ short As[64 * 72];
    __shared__ short Bs[64 * 72];

    const int t = threadIdx.x;
    const int lane = t & 63, wave = t >> 6;
    const int lr = lane & 15, kh = lane >> 4;
    const int n0 = blockIdx.x * 64;
    const int sr = t >> 2, sc = (t & 3) * 16;

    const short* Arow = A + (size_t)sr * 3072 + sc;
    const float* Brow = B + (size_t)(n0 + sr) * 3072 + sc;

    f32x4 acc[4] = {};

    // prologue: tile 0 into regs
    bf16x8 pa0 = *(const bf16x8*)(Arow);
    bf16x8 pa1 = *(const bf16x8*)(Arow + 8);
    f32x4 pb0 = *(const f32x4*)(Brow);
    f32x4 pb1 = *(const f32x4*)(Brow + 4);
    f32x4 pb2 = *(const f32x4*)(Brow + 8);
    f32x4 pb3 = *(const f32x4*)(Brow + 12);

    for (int kt = 0; kt < 48; ++kt) {
        // write staged regs -> LDS
        *(bf16x8*)(As + sr * 72 + sc)     = pa0;
        *(bf16x8*)(As + sr * 72 + sc + 8) = pa1;
        {
            bf16x8 q0, q1;
            q0[0] = f2bf(pb0[0]); q0[1] = f2bf(pb0[1]); q0[2] = f2bf(pb0[2]); q0[3] = f2bf(pb0[3]);
            q0[4] = f2bf(pb1[0]); q0[5] = f2bf(pb1[1]); q0[6] = f2bf(pb1[2]); q0[7] = f2bf(pb1[3]);
            q1[0] = f2bf(pb2[0]); q1[1] = f2bf(pb2[1]); q1[2] = f2bf(pb2[2]); q1[3] = f2bf(pb2[3]);
            q1[4] = f2bf(pb3[0]); q1[5] = f2bf(pb3[1]); q1[6] = f2bf(pb3[2]); q1[7] = f2bf(pb3[3]);
            *(bf16x8*)(Bs + sr * 72 + sc)     = q0;
            *(bf16x8*)(Bs + sr * 72 + sc + 8) = q1;
        }
        __syncthreads();

        // prefetch tile kt+1 into regs (overlaps the MFMA phase below)
        if (kt + 1 < 48) {
            const int kn = (kt + 1) * 64;
            pa0 = *(const bf16x8*)(Arow + kn);
            pa1 = *(const bf16x8*)(Arow + kn + 8);
            pb0 = *(const f32x4*)(Brow + kn);
            pb1 = *(const f32x4*)(Brow + kn + 4);
            pb2 = *(const f32x4*)(Brow + kn + 8);
            pb3 = *(const f32x4*)(Brow + kn + 12);
        }

#pragma unroll
        for (int kk = 0; kk < 64; kk += 32) {
            bf16x8 af[4], bfr;
#pragma unroll
            for (int mi = 0; mi < 4; ++mi)
                af[mi] = *(const bf16x8*)(As + (mi * 16 + lr) * 72 + kk + kh * 8);
            bfr = *(const bf16x8*)(Bs + (wave * 16 + lr) * 72 + kk + kh * 8);
#pragma unroll
            for (int mi = 0; mi < 4; ++mi)
                acc[mi] = __builtin_amdgcn_mfma_f32_16x16x32_bf16(af[mi], bfr, acc[mi], 0, 0, 0);
        }
        __syncthreads();
    }

    const int col = n0 + wave * 16 + lr;
    const float bb = bias[col];
#pragma unroll
    for (int mi = 0; mi < 4; ++mi)
#pragma unroll
        for (int r = 0; r < 4; ++r) {
            const int row = mi * 16 + kh * 4 + r;
            logits[(size_t)row * VOC + col] = acc[mi][r] + bb;
        }
}

// ---------------------------------------------------------------------------
extern "C" void kernel_launch(void* const* d_in, const int* in_sizes, int n_in,
                              void* d_out, int out_size, void* d_ws, size_t ws_size,
                              hipStream_t stream)
{
    const int*   ids    = (const int*)d_in[0];
    const float* hidden = (const float*)d_in[1];
    const float* enc    = (const float*)d_in[2];
    const float* emb    = (const float*)d_in[3];
    const float* attnW  = (const float*)d_in[4];
    const float* attnb  = (const float*)d_in[5];
    const float* vvec   = (const float*)d_in[6];
    const float* w_ih   = (const float*)d_in[7];
    const float* w_hh   = (const float*)d_in[8];
    const float* b_ih   = (const float*)d_in[9];
    const float* b_hh   = (const float*)d_in[10];
    const float* out_W  = (const float*)d_in[11];
    const float* out_b  = (const float*)d_in[12];

    float* out        = (float*)d_out;
    float* out_logits = out;
    float* out_hnew   = out + (size_t)BSZ * VOC;
    float* out_attn   = out_hnew + (size_t)BSZ * Hdim;

    float* ws = (float*)d_ws;
    short* enc_bf    = (short*)ws;
    short* attnW_bf  = (short*)(ws + 4194304);
    short* hidden_bf = (short*)(ws + 5242880);
    float* ws_u4  = ws + 5275648;
    float* ws_sp  = ws_u4 + 262144;
    short* x_bf   = (short*)(ws_sp + 65536);
    short* oc_bf  = (short*)(ws_sp + 131072);
    float* ws_gx4 = ws_sp + 229376;
    float* ws_gh4 = ws_gx4 + 786432;

    // 1. f32 -> bf16 one-pass conversion
    convert_bf16<<<dim3(1024), 256, 0, stream>>>(
        enc, attnW, hidden, enc_bf, attnW_bf, hidden_bf);

    // 2. u partials: hidden_bf @ W2_bf^T (split-K x4, 32 blocks)
    ugemm<<<dim3(Hdim / 128, 4), 256, 0, stream>>>(
        hidden_bf, attnW_bf + Hdim, ws_u4);

    // 3. fused energy GEMM + u-combine + tanh + v-reduction (gload_lds)
    attn_scores_mfma<<<dim3(LSEQ / 2, 8), 512, 0, stream>>>(
        enc_bf, attnW_bf, ws_u4, attnb, vvec, ws_sp);

    // 4. softmax + weighted context + embedding (256 blocks)
    softmax_weighted<<<dim3(BSZ, 4), 128, 0, stream>>>(
        ws_sp, enc_bf, ids, emb, out_attn, x_bf, oc_bf);

    // 5. merged GRU gate GEMMs (LDS-staged, split-K x4, 192 blocks)
    gxgh_gemm<<<dim3(48, 4), 256, 0, stream>>>(
        x_bf, w_ih, hidden_bf, w_hh, ws_gx4, ws_gh4);

    // 6. GRU elementwise
    gru_kernel<<<dim3(BSZ * Hdim / 256), 256, 0, stream>>>(
        ws_gx4, ws_gh4, b_ih, b_hh, hidden, out_hnew, oc_bf);

    // 7. output projection, direct write + reg-prefetch (500 blocks)
    outproj_direct<<<dim3(VOC / 64), 256, 0, stream>>>(
        oc_bf, out_W, out_b, out_logits);
}

// Round 8
// 174.141 us; speedup vs baseline: 1.3322x; 1.0673x over previous
//
#include <hip/hip_runtime.h>
#include <math.h>

#define Hdim 1024
#define VOC 32000
#define LSEQ 128
#define BSZ 64

typedef __attribute__((ext_vector_type(8))) short bf16x8;
typedef __attribute__((ext_vector_type(4))) float f32x4;

__device__ __forceinline__ float fast_tanhf(float x) {
    return 1.0f - 2.0f / (__expf(2.0f * x) + 1.0f);
}
__device__ __forceinline__ float sigmoidf(float x) {
    return 1.0f / (1.0f + __expf(-x));
}
__device__ __forceinline__ short f2bf(float f) {
    unsigned u = __float_as_uint(f);
    unsigned r = (u + 0x7fffu + ((u >> 16) & 1u)) >> 16;
    return (short)r;
}

// async global->LDS, 16 bytes per lane (dest must be linear: base + lane*16)
__device__ __forceinline__ void gl_lds16(const short* g, short* l) {
    __builtin_amdgcn_global_load_lds(
        (const __attribute__((address_space(1))) unsigned*)g,
        (__attribute__((address_space(3))) unsigned*)l, 16, 0, 0);
}

// 16 consecutive f32 -> 16 bf16 at dst (2x 16B stores)
__device__ __forceinline__ void stage16(const float* __restrict__ src, short* dst) {
    f32x4 v0 = *(const f32x4*)(src);
    f32x4 v1 = *(const f32x4*)(src + 4);
    f32x4 v2 = *(const f32x4*)(src + 8);
    f32x4 v3 = *(const f32x4*)(src + 12);
    bf16x8 p0, p1;
    p0[0] = f2bf(v0[0]); p0[1] = f2bf(v0[1]); p0[2] = f2bf(v0[2]); p0[3] = f2bf(v0[3]);
    p0[4] = f2bf(v1[0]); p0[5] = f2bf(v1[1]); p0[6] = f2bf(v1[2]); p0[7] = f2bf(v1[3]);
    p1[0] = f2bf(v2[0]); p1[1] = f2bf(v2[1]); p1[2] = f2bf(v2[2]); p1[3] = f2bf(v2[3]);
    p1[4] = f2bf(v3[0]); p1[5] = f2bf(v3[1]); p1[6] = f2bf(v3[2]); p1[7] = f2bf(v3[3]);
    *(bf16x8*)(dst) = p0;
    *(bf16x8*)(dst + 8) = p1;
}

// ---------------------------------------------------------------------------
// One-pass f32 -> bf16 conversion of enc, attn_W, hidden (grid-stride).
// ---------------------------------------------------------------------------
__global__ __launch_bounds__(256) void convert_bf16(
    const float* __restrict__ enc, const float* __restrict__ attnW,
    const float* __restrict__ hidden,
    short* __restrict__ enc_bf, short* __restrict__ attnW_bf,
    short* __restrict__ hidden_bf)
{
    const int NG_ENC = (LSEQ * BSZ * Hdim) / 8;   // 1048576
    const int NG_AW  = (Hdim * 2 * Hdim) / 8;     // 262144
    const int NG_H   = (BSZ * Hdim) / 8;          // 8192
    const int total = NG_ENC + NG_AW + NG_H;
    for (int g = blockIdx.x * 256 + threadIdx.x; g < total; g += gridDim.x * 256) {
        const float* src; short* dst; int idx;
        if (g < NG_ENC)              { src = enc;    dst = enc_bf;    idx = g; }
        else if (g < NG_ENC + NG_AW) { src = attnW;  dst = attnW_bf;  idx = g - NG_ENC; }
        else                         { src = hidden; dst = hidden_bf; idx = g - NG_ENC - NG_AW; }
        f32x4 a = *(const f32x4*)(src + (size_t)idx * 8);
        f32x4 b = *(const f32x4*)(src + (size_t)idx * 8 + 4);
        bf16x8 p;
        p[0] = f2bf(a[0]); p[1] = f2bf(a[1]); p[2] = f2bf(a[2]); p[3] = f2bf(a[3]);
        p[4] = f2bf(b[0]); p[5] = f2bf(b[1]); p[6] = f2bf(b[2]); p[7] = f2bf(b[3]);
        *(bf16x8*)(dst + (size_t)idx * 8) = p;
    }
}

// ---------------------------------------------------------------------------
// u partial GEMM: u4[s] = hidden_bf @ W2_bf^T  (split-K x4, bf16 operands)
// ---------------------------------------------------------------------------
__global__ __launch_bounds__(256) void ugemm(
    const short* __restrict__ A,    // hidden_bf [64,1024]
    const short* __restrict__ B,    // attnW_bf + Hdim, ld 2048
    float* __restrict__ C)          // [4][64,1024]
{
    __shared__ short As[64 * 72];
    __shared__ short Bs[128 * 72];

    const int t = threadIdx.x;
    const int lane = t & 63, wave = t >> 6;
    const int lr = lane & 15, kh = lane >> 4;
    const int n0 = blockIdx.x * 128;
    const int kstart = blockIdx.y * 256;
    float* Cp = C + (size_t)blockIdx.y * (BSZ * Hdim);

    const int ar = t >> 2, ac = (t & 3) * 16;
    const int br = t >> 1, bc = (t & 1) * 32;

    f32x4 acc[4][2] = {};

    for (int k0 = 0; k0 < 256; k0 += 64) {
        const int kg = kstart + k0;
        {
            const short* s = A + (size_t)ar * Hdim + kg + ac;
            *(bf16x8*)(As + ar * 72 + ac)     = *(const bf16x8*)(s);
            *(bf16x8*)(As + ar * 72 + ac + 8) = *(const bf16x8*)(s + 8);
        }
        {
            const short* s = B + (size_t)(n0 + br) * (2 * Hdim) + kg + bc;
            short* d = Bs + br * 72 + bc;
            *(bf16x8*)(d)      = *(const bf16x8*)(s);
            *(bf16x8*)(d + 8)  = *(const bf16x8*)(s + 8);
            *(bf16x8*)(d + 16) = *(const bf16x8*)(s + 16);
            *(bf16x8*)(d + 24) = *(const bf16x8*)(s + 24);
        }
        __syncthreads();
#pragma unroll
        for (int kk = 0; kk < 64; kk += 32) {
            bf16x8 af[4], bfr[2];
#pragma unroll
            for (int mi = 0; mi < 4; ++mi)
                af[mi] = *(const bf16x8*)(As + (mi * 16 + lr) * 72 + kk + kh * 8);
#pragma unroll
            for (int ni = 0; ni < 2; ++ni)
                bfr[ni] = *(const bf16x8*)(Bs + (wave * 32 + ni * 16 + lr) * 72 + kk + kh * 8);
#pragma unroll
            for (int mi = 0; mi < 4; ++mi)
#pragma unroll
                for (int ni = 0; ni < 2; ++ni)
                    acc[mi][ni] = __builtin_amdgcn_mfma_f32_16x16x32_bf16(
                        af[mi], bfr[ni], acc[mi][ni], 0, 0, 0);
        }
        __syncthreads();
    }

#pragma unroll
    for (int mi = 0; mi < 4; ++mi)
#pragma unroll
        for (int ni = 0; ni < 2; ++ni) {
            const int col = n0 + wave * 32 + ni * 16 + lr;
#pragma unroll
            for (int r = 0; r < 4; ++r) {
                const int row = mi * 16 + kh * 4 + r;
                Cp[(size_t)row * Hdim + col] = acc[mi][ni][r];
            }
        }
}

// ---------------------------------------------------------------------------
// Fused attention scores, 128x128 tile, 512 threads = 8 waves (2x4).
// Staging via global_load_lds (m97 pattern): linear [128][64] bf16 tiles.
// ---------------------------------------------------------------------------
__global__ __launch_bounds__(512) void attn_scores_mfma(
    const short* __restrict__ enc_bf,   // [8192, 1024]
    const short* __restrict__ W1_bf,    // ld 2048, cols [0,1024)
    const float* __restrict__ u4,       // [4][64, 1024]
    const float* __restrict__ attnb,    // [1024]
    const float* __restrict__ vvec,     // [1024]
    float* __restrict__ scores_part)    // [8][8192]
{
    __shared__ short As[128 * 64];      // linear: row*64 + k
    __shared__ short Bs[128 * 64];
    __shared__ float red[8][64];
    __shared__ float u_lds[64 * 128];

    const int t = threadIdx.x;
    const int lane = t & 63, wave = t >> 6;     // 8 waves
    const int wr = wave >> 2, wc = wave & 3;    // 2 x 4 wave grid
    const int lr = lane & 15, kh = lane >> 4;
    const int m0 = blockIdx.x * 128;
    const int n0 = blockIdx.y * 128;

    // gload_lds geometry: byte offset o covers row o>>7, short-col (o&127)>>1.
    const int o1 = t * 16;            // 0..8191
    const int o2 = 8192 + t * 16;     // 8192..16383
    const int r1 = o1 >> 7, c1 = (o1 & 127) >> 1;
    const int r2 = o2 >> 7, c2 = (o2 & 127) >> 1;

    // u-sum table for this block's 128 h-cols (covered by first sync)
    for (int i = t; i < 64 * 128; i += 512) {
        const int b = i >> 7, hl = i & 127;
        const size_t g = (size_t)b * Hdim + n0 + hl;
        u_lds[i] = u4[g] + u4[65536 + g] + u4[2 * 65536 + g] + u4[3 * 65536 + g]
                 + attnb[n0 + hl];
    }

    f32x4 acc[4][2] = {};

    for (int kg = 0; kg < Hdim; kg += 64) {
        gl_lds16(enc_bf + (size_t)(m0 + r1) * Hdim + kg + c1, As + (o1 >> 1));
        gl_lds16(enc_bf + (size_t)(m0 + r2) * Hdim + kg + c2, As + (o2 >> 1));
        gl_lds16(W1_bf + (size_t)(n0 + r1) * (2 * Hdim) + kg + c1, Bs + (o1 >> 1));
        gl_lds16(W1_bf + (size_t)(n0 + r2) * (2 * Hdim) + kg + c2, Bs + (o2 >> 1));
        __syncthreads();
#pragma unroll
        for (int kk = 0; kk < 64; kk += 32) {
            bf16x8 af[4], bfr[2];
#pragma unroll
            for (int mi = 0; mi < 4; ++mi)
                af[mi] = *(const bf16x8*)(As + (wr * 64 + mi * 16 + lr) * 64 + kk + kh * 8);
#pragma unroll
            for (int ni = 0; ni < 2; ++ni)
                bfr[ni] = *(const bf16x8*)(Bs + (wc * 32 + ni * 16 + lr) * 64 + kk + kh * 8);
#pragma unroll
            for (int mi = 0; mi < 4; ++mi)
#pragma unroll
                for (int ni = 0; ni < 2; ++ni)
                    acc[mi][ni] = __builtin_amdgcn_mfma_f32_16x16x32_bf16(
                        af[mi], bfr[ni], acc[mi][ni], 0, 0, 0);
        }
        __syncthreads();
    }

    float sv[16];
#pragma unroll
    for (int mi = 0; mi < 4; ++mi)
#pragma unroll
        for (int r = 0; r < 4; ++r) {
            const int lrow = mi * 16 + kh * 4 + r;
            const int b = lrow;
            float s = 0.0f;
#pragma unroll
            for (int ni = 0; ni < 2; ++ni) {
                const int hl = wc * 32 + ni * 16 + lr;
                const float e = fast_tanhf(acc[mi][ni][r] + u_lds[b * 128 + hl]);
                s += e * vvec[n0 + hl];
            }
            sv[mi * 4 + r] = s;
        }
#pragma unroll
    for (int i = 0; i < 16; ++i) {
#pragma unroll
        for (int d = 1; d < 16; d <<= 1)
            sv[i] += __shfl_xor(sv[i], d, 64);
    }
    if (lr == 0) {
#pragma unroll
        for (int mi = 0; mi < 4; ++mi)
#pragma unroll
            for (int r = 0; r < 4; ++r)
                red[wave][mi * 16 + kh * 4 + r] = sv[mi * 4 + r];
    }
    __syncthreads();
    if (t < 128) {
        const int wrr = t >> 6, lrow = t & 63;
        scores_part[(size_t)blockIdx.y * (LSEQ * BSZ) + m0 + t] =
            red[wrr * 4 + 0][lrow] + red[wrr * 4 + 1][lrow] +
            red[wrr * 4 + 2][lrow] + red[wrr * 4 + 3][lrow];
    }
}

// ---------------------------------------------------------------------------
// Fused softmax + weighted context + embedding. grid(64 b, 4 hg), 128 thr.
// ---------------------------------------------------------------------------
__global__ __launch_bounds__(128) void softmax_weighted(
    const float* __restrict__ sp,       // [8][8192]
    const short* __restrict__ enc_bf,   // [8192, 1024]
    const int* __restrict__ ids,
    const float* __restrict__ emb,
    float* __restrict__ attn_out,       // [B, L]
    short* __restrict__ x_bf,           // [64, 2048]
    short* __restrict__ oc_bf)          // [64, 3072]
{
    const int b = blockIdx.x, hg = blockIdx.y, t = threadIdx.x;
    __shared__ float aw[LSEQ];
    __shared__ float red[LSEQ];

    if (hg == 0) {
        const int id = ids[b];
        const int h = t * 8;
        f32x4 e0 = *(const f32x4*)(emb + (size_t)id * Hdim + h);
        f32x4 e1 = *(const f32x4*)(emb + (size_t)id * Hdim + h + 4);
        bf16x8 p;
        p[0] = f2bf(e0[0]); p[1] = f2bf(e0[1]); p[2] = f2bf(e0[2]); p[3] = f2bf(e0[3]);
        p[4] = f2bf(e1[0]); p[5] = f2bf(e1[1]); p[6] = f2bf(e1[2]); p[7] = f2bf(e1[3]);
        *(bf16x8*)(x_bf + (size_t)b * 2048 + h) = p;
        *(bf16x8*)(oc_bf + (size_t)b * 3072 + 2048 + h) = p;
    }

    float s = 0.0f;
#pragma unroll
    for (int g = 0; g < 8; ++g) s += sp[g * (LSEQ * BSZ) + t * 64 + b];
    red[t] = s;
    __syncthreads();
    for (int off = 64; off > 0; off >>= 1) {
        if (t < off) red[t] = fmaxf(red[t], red[t + off]);
        __syncthreads();
    }
    const float mx = red[0];
    __syncthreads();
    const float e = __expf(s - mx);
    red[t] = e;
    __syncthreads();
    for (int off = 64; off > 0; off >>= 1) {
        if (t < off) red[t] += red[t + off];
        __syncthreads();
    }
    const float p = e / red[0];
    aw[t] = p;
    if (hg == 0) attn_out[(size_t)b * LSEQ + t] = p;
    __syncthreads();

    const int h = hg * 256 + t * 2;
    float a0 = 0.0f, a1 = 0.0f;
#pragma unroll 8
    for (int l = 0; l < LSEQ; ++l) {
        const unsigned w = *(const unsigned*)(enc_bf + ((size_t)l * BSZ + b) * Hdim + h);
        const float pw = aw[l];
        a0 = fmaf(pw, __uint_as_float(w << 16), a0);
        a1 = fmaf(pw, __uint_as_float(w & 0xffff0000u), a1);
    }
    const unsigned packed = (unsigned)(unsigned short)f2bf(a0)
                          | ((unsigned)(unsigned short)f2bf(a1) << 16);
    *(unsigned*)(x_bf + (size_t)b * 2048 + 1024 + h) = packed;
    *(unsigned*)(oc_bf + (size_t)b * 3072 + 1024 + h) = packed;
}

// ---------------------------------------------------------------------------
// Streaming skinny GEMM body (512 thr = 8 waves, 64x64 tile, BK=64):
// double-buffered LDS, ONE barrier per k-tile. Per iter: issue next tile's
// global->reg loads, barrier, MFMA from buf[cur], write regs->buf[cur^1].
// The vmcnt wait sits just before the LDS write, so HBM issue overlaps the
// whole MFMA phase (T3-minimum 2-phase schedule).
// A bf16 [64,K] (L2-resident), B f32 [N,K] streamed once.
// ---------------------------------------------------------------------------
__device__ __forceinline__ void sgemm_body(
    const short* __restrict__ A, int lda,
    const float* __restrict__ B, int ldb,
    const float* __restrict__ bias,
    float* __restrict__ C, int ldc,
    int n0, int kstart, int klen)
{
    __shared__ short As[2][64 * 72];   // 72-pad: 2-way bank alias (free, m136)
    __shared__ short Bs[2][64 * 72];

    const int t = threadIdx.x;               // 0..511
    const int lane = t & 63, wave = t >> 6;  // 8 waves
    const int wm = wave >> 2, wn = wave & 3; // 2 x 4 wave grid
    const int lr = lane & 15, kh = lane >> 4;

    const int sr = t >> 3, sc = (t & 7) * 8; // staging: 64 rows x 64 cols, 8/thread
    const short* Ap = A + (size_t)sr * lda + kstart + sc;
    const float* Bp = B + (size_t)(n0 + sr) * ldb + kstart + sc;

    const int nkt = klen >> 6;

    // prologue: k-tile 0 -> regs -> buf 0
    bf16x8 pa = *(const bf16x8*)(Ap);
    f32x4 pb0 = *(const f32x4*)(Bp);
    f32x4 pb1 = *(const f32x4*)(Bp + 4);
    *(bf16x8*)(&As[0][sr * 72 + sc]) = pa;
    {
        bf16x8 q;
        q[0] = f2bf(pb0[0]); q[1] = f2bf(pb0[1]); q[2] = f2bf(pb0[2]); q[3] = f2bf(pb0[3]);
        q[4] = f2bf(pb1[0]); q[5] = f2bf(pb1[1]); q[6] = f2bf(pb1[2]); q[7] = f2bf(pb1[3]);
        *(bf16x8*)(&Bs[0][sr * 72 + sc]) = q;
    }

    f32x4 acc[2] = {};

    for (int kt = 0; kt < nkt; ++kt) {
        const int cur = kt & 1;
        if (kt + 1 < nkt) {                   // issue next tile's loads
            const int kn = (kt + 1) * 64;
            pa  = *(const bf16x8*)(Ap + kn);
            pb0 = *(const f32x4*)(Bp + kn);
            pb1 = *(const f32x4*)(Bp + kn + 4);
        }
        __syncthreads();                      // buf[cur] ready
#pragma unroll
        for (int kk = 0; kk < 64; kk += 32) {
            bf16x8 af0 = *(const bf16x8*)(&As[cur][(wm * 32 + lr) * 72 + kk + kh * 8]);
            bf16x8 af1 = *(const bf16x8*)(&As[cur][(wm * 32 + 16 + lr) * 72 + kk + kh * 8]);
            bf16x8 bfr = *(const bf16x8*)(&Bs[cur][(wn * 16 + lr) * 72 + kk + kh * 8]);
            acc[0] = __builtin_amdgcn_mfma_f32_16x16x32_bf16(af0, bfr, acc[0], 0, 0, 0);
            acc[1] = __builtin_amdgcn_mfma_f32_16x16x32_bf16(af1, bfr, acc[1], 0, 0, 0);
        }
        if (kt + 1 < nkt) {                   // write regs -> other buffer
            const int nxt = cur ^ 1;
            *(bf16x8*)(&As[nxt][sr * 72 + sc]) = pa;
            bf16x8 q;
            q[0] = f2bf(pb0[0]); q[1] = f2bf(pb0[1]); q[2] = f2bf(pb0[2]); q[3] = f2bf(pb0[3]);
            q[4] = f2bf(pb1[0]); q[5] = f2bf(pb1[1]); q[6] = f2bf(pb1[2]); q[7] = f2bf(pb1[3]);
            *(bf16x8*)(&Bs[nxt][sr * 72 + sc]) = q;
        }
    }

    const int col = n0 + wn * 16 + lr;
    const float bb = bias ? bias[col] : 0.0f;
#pragma unroll
    for (int mi = 0; mi < 2; ++mi)
#pragma unroll
        for (int r = 0; r < 4; ++r) {
            const int row = wm * 32 + mi * 16 + kh * 4 + r;
            C[(size_t)row * ldc + col] = acc[mi][r] + bb;
        }
}

// Output projection: logits = oc_bf @ out_W^T + out_b. grid(500), 512 thr.
__global__ __launch_bounds__(512) void outproj_stream(
    const short* __restrict__ A, const float* __restrict__ B,
    const float* __restrict__ bias, float* __restrict__ logits)
{
    sgemm_body(A, 3 * Hdim, B, 3 * Hdim, bias, logits, VOC,
               blockIdx.x * 64, 0, 3 * Hdim);
}

// Merged GRU gate GEMMs, split-K x4 partials. grid(96, 4), 512 thr.
__global__ __launch_bounds__(512) void gxgh_stream(
    const short* __restrict__ x_bf, const float* __restrict__ w_ih,
    const short* __restrict__ hidden_bf, const float* __restrict__ w_hh,
    float* __restrict__ gx4, float* __restrict__ gh4)
{
    const size_t P = (size_t)BSZ * 3 * Hdim;
    if (blockIdx.x < 48)
        sgemm_body(x_bf, 2 * Hdim, w_ih, 2 * Hdim, nullptr,
                   gx4 + blockIdx.y * P, 3 * Hdim,
                   blockIdx.x * 64, blockIdx.y * 512, 512);
    else
        sgemm_body(hidden_bf, Hdim, w_hh, Hdim, nullptr,
                   gh4 + blockIdx.y * P, 3 * Hdim,
                   (blockIdx.x - 48) * 64, blockIdx.y * 256, 256);
}

// ---------------------------------------------------------------------------
// GRU elementwise; sums 4 split-K partials + biases; bf16 out_cat write.
// ---------------------------------------------------------------------------
__global__ __launch_bounds__(256) void gru_kernel(
    const float* __restrict__ gx4, const float* __restrict__ gh4,
    const float* __restrict__ b_ih, const float* __restrict__ b_hh,
    const float* __restrict__ h0,
    float* __restrict__ hnew_out, short* __restrict__ oc_bf)
{
    const int idx = blockIdx.x * 256 + threadIdx.x;
    const int b = idx >> 10, h = idx & 1023;
    const size_t g3 = (size_t)b * (3 * Hdim);
    const size_t P = (size_t)BSZ * 3 * Hdim;
    float xr = b_ih[h], xz = b_ih[Hdim + h], xn = b_ih[2 * Hdim + h];
    float hr = b_hh[h], hz = b_hh[Hdim + h], hn = b_hh[2 * Hdim + h];
#pragma unroll
    for (int s = 0; s < 4; ++s) {
        xr += gx4[s * P + g3 + h];
        xz += gx4[s * P + g3 + Hdim + h];
        xn += gx4[s * P + g3 + 2 * Hdim + h];
        hr += gh4[s * P + g3 + h];
        hz += gh4[s * P + g3 + Hdim + h];
        hn += gh4[s * P + g3 + 2 * Hdim + h];
    }
    const float r = sigmoidf(xr + hr);
    const float z = sigmoidf(xz + hz);
    const float n = fast_tanhf(xn + r * hn);
    const float hv = (1.0f - z) * n + z * h0[(size_t)b * Hdim + h];
    hnew_out[(size_t)b * Hdim + h] = hv;
    oc_bf[g3 + h] = f2bf(hv);
}

// ---------------------------------------------------------------------------
extern "C" void kernel_launch(void* const* d_in, const int* in_sizes, int n_in,
                              void* d_out, int out_size, void* d_ws, size_t ws_size,
                              hipStream_t stream)
{
    const int*   ids    = (const int*)d_in[0];
    const float* hidden = (const float*)d_in[1];
    const float* enc    = (const float*)d_in[2];
    const float* emb    = (const float*)d_in[3];
    const float* attnW  = (const float*)d_in[4];
    const float* attnb  = (const float*)d_in[5];
    const float* vvec   = (const float*)d_in[6];
    const float* w_ih   = (const float*)d_in[7];
    const float* w_hh   = (const float*)d_in[8];
    const float* b_ih   = (const float*)d_in[9];
    const float* b_hh   = (const float*)d_in[10];
    const float* out_W  = (const float*)d_in[11];
    const float* out_b  = (const float*)d_in[12];

    float* out        = (float*)d_out;
    float* out_logits = out;
    float* out_hnew   = out + (size_t)BSZ * VOC;
    float* out_attn   = out_hnew + (size_t)BSZ * Hdim;

    float* ws = (float*)d_ws;
    short* enc_bf    = (short*)ws;
    short* attnW_bf  = (short*)(ws + 4194304);
    short* hidden_bf = (short*)(ws + 5242880);
    float* ws_u4  = ws + 5275648;
    float* ws_sp  = ws_u4 + 262144;
    short* x_bf   = (short*)(ws_sp + 65536);
    short* oc_bf  = (short*)(ws_sp + 131072);
    float* ws_gx4 = ws_sp + 229376;
    float* ws_gh4 = ws_gx4 + 786432;

    // 1. f32 -> bf16 one-pass conversion
    convert_bf16<<<dim3(1024), 256, 0, stream>>>(
        enc, attnW, hidden, enc_bf, attnW_bf, hidden_bf);

    // 2. u partials: hidden_bf @ W2_bf^T (split-K x4, 32 blocks)
    ugemm<<<dim3(Hdim / 128, 4), 256, 0, stream>>>(
        hidden_bf, attnW_bf + Hdim, ws_u4);

    // 3. fused energy GEMM + u-combine + tanh + v-reduction (gload_lds)
    attn_scores_mfma<<<dim3(LSEQ / 2, 8), 512, 0, stream>>>(
        enc_bf, attnW_bf, ws_u4, attnb, vvec, ws_sp);

    // 4. softmax + weighted context + embedding (256 blocks)
    softmax_weighted<<<dim3(BSZ, 4), 128, 0, stream>>>(
        ws_sp, enc_bf, ids, emb, out_attn, x_bf, oc_bf);

    // 5. merged GRU gate GEMMs, double-buffered streaming (384 blocks)
    gxgh_stream<<<dim3(96, 4), 512, 0, stream>>>(
        x_bf, w_ih, hidden_bf, w_hh, ws_gx4, ws_gh4);

    // 6. GRU elementwise
    gru_kernel<<<dim3(BSZ * Hdim / 256), 256, 0, stream>>>(
        ws_gx4, ws_gh4, b_ih, b_hh, hidden, out_hnew, oc_bf);

    // 7. output projection, double-buffered streaming (500 blocks)
    outproj_stream<<<dim3(VOC / 64), 512, 0, stream>>>(
        oc_bf, out_W, out_b, out_logits);
}

// Round 9
// 172.276 us; speedup vs baseline: 1.3467x; 1.0108x over previous
//
#include <hip/hip_runtime.h>
#include <math.h>

#define Hdim 1024
#define VOC 32000
#define LSEQ 128
#define BSZ 64

typedef __attribute__((ext_vector_type(8))) short bf16x8;
typedef __attribute__((ext_vector_type(4))) float f32x4;

__device__ __forceinline__ float fast_tanhf(float x) {
    return 1.0f - 2.0f / (__expf(2.0f * x) + 1.0f);
}
__device__ __forceinline__ float sigmoidf(float x) {
    return 1.0f / (1.0f + __expf(-x));
}
__device__ __forceinline__ short f2bf(float f) {
    unsigned u = __float_as_uint(f);
    unsigned r = (u + 0x7fffu + ((u >> 16) & 1u)) >> 16;
    return (short)r;
}

// async global->LDS, 16 bytes per lane (dest must be linear: base + lane*16)
__device__ __forceinline__ void gl_lds16(const short* g, short* l) {
    __builtin_amdgcn_global_load_lds(
        (const __attribute__((address_space(1))) unsigned*)g,
        (__attribute__((address_space(3))) unsigned*)l, 16, 0, 0);
}

// ---------------------------------------------------------------------------
// One-pass f32 -> bf16 conversion of enc, attn_W, hidden (grid-stride).
// ---------------------------------------------------------------------------
__global__ __launch_bounds__(256) void convert_bf16(
    const float* __restrict__ enc, const float* __restrict__ attnW,
    const float* __restrict__ hidden,
    short* __restrict__ enc_bf, short* __restrict__ attnW_bf,
    short* __restrict__ hidden_bf)
{
    const int NG_ENC = (LSEQ * BSZ * Hdim) / 8;   // 1048576
    const int NG_AW  = (Hdim * 2 * Hdim) / 8;     // 262144
    const int NG_H   = (BSZ * Hdim) / 8;          // 8192
    const int total = NG_ENC + NG_AW + NG_H;
    for (int g = blockIdx.x * 256 + threadIdx.x; g < total; g += gridDim.x * 256) {
        const float* src; short* dst; int idx;
        if (g < NG_ENC)              { src = enc;    dst = enc_bf;    idx = g; }
        else if (g < NG_ENC + NG_AW) { src = attnW;  dst = attnW_bf;  idx = g - NG_ENC; }
        else                         { src = hidden; dst = hidden_bf; idx = g - NG_ENC - NG_AW; }
        f32x4 a = *(const f32x4*)(src + (size_t)idx * 8);
        f32x4 b = *(const f32x4*)(src + (size_t)idx * 8 + 4);
        bf16x8 p;
        p[0] = f2bf(a[0]); p[1] = f2bf(a[1]); p[2] = f2bf(a[2]); p[3] = f2bf(a[3]);
        p[4] = f2bf(b[0]); p[5] = f2bf(b[1]); p[6] = f2bf(b[2]); p[7] = f2bf(b[3]);
        *(bf16x8*)(dst + (size_t)idx * 8) = p;
    }
}

// ---------------------------------------------------------------------------
// u partial GEMM: u4[s] = hidden_bf @ W2_bf^T  (split-K x4, bf16 operands)
// ---------------------------------------------------------------------------
__global__ __launch_bounds__(256) void ugemm(
    const short* __restrict__ A,    // hidden_bf [64,1024]
    const short* __restrict__ B,    // attnW_bf + Hdim, ld 2048
    float* __restrict__ C)          // [4][64,1024]
{
    __shared__ short As[64 * 72];
    __shared__ short Bs[128 * 72];

    const int t = threadIdx.x;
    const int lane = t & 63, wave = t >> 6;
    const int lr = lane & 15, kh = lane >> 4;
    const int n0 = blockIdx.x * 128;
    const int kstart = blockIdx.y * 256;
    float* Cp = C + (size_t)blockIdx.y * (BSZ * Hdim);

    const int ar = t >> 2, ac = (t & 3) * 16;
    const int br = t >> 1, bc = (t & 1) * 32;

    f32x4 acc[4][2] = {};

    for (int k0 = 0; k0 < 256; k0 += 64) {
        const int kg = kstart + k0;
        {
            const short* s = A + (size_t)ar * Hdim + kg + ac;
            *(bf16x8*)(As + ar * 72 + ac)     = *(const bf16x8*)(s);
            *(bf16x8*)(As + ar * 72 + ac + 8) = *(const bf16x8*)(s + 8);
        }
        {
            const short* s = B + (size_t)(n0 + br) * (2 * Hdim) + kg + bc;
            short* d = Bs + br * 72 + bc;
            *(bf16x8*)(d)      = *(const bf16x8*)(s);
            *(bf16x8*)(d + 8)  = *(const bf16x8*)(s + 8);
            *(bf16x8*)(d + 16) = *(const bf16x8*)(s + 16);
            *(bf16x8*)(d + 24) = *(const bf16x8*)(s + 24);
        }
        __syncthreads();
#pragma unroll
        for (int kk = 0; kk < 64; kk += 32) {
            bf16x8 af[4], bfr[2];
#pragma unroll
            for (int mi = 0; mi < 4; ++mi)
                af[mi] = *(const bf16x8*)(As + (mi * 16 + lr) * 72 + kk + kh * 8);
#pragma unroll
            for (int ni = 0; ni < 2; ++ni)
                bfr[ni] = *(const bf16x8*)(Bs + (wave * 32 + ni * 16 + lr) * 72 + kk + kh * 8);
#pragma unroll
            for (int mi = 0; mi < 4; ++mi)
#pragma unroll
                for (int ni = 0; ni < 2; ++ni)
                    acc[mi][ni] = __builtin_amdgcn_mfma_f32_16x16x32_bf16(
                        af[mi], bfr[ni], acc[mi][ni], 0, 0, 0);
        }
        __syncthreads();
    }

#pragma unroll
    for (int mi = 0; mi < 4; ++mi)
#pragma unroll
        for (int ni = 0; ni < 2; ++ni) {
            const int col = n0 + wave * 32 + ni * 16 + lr;
#pragma unroll
            for (int r = 0; r < 4; ++r) {
                const int row = mi * 16 + kh * 4 + r;
                Cp[(size_t)row * Hdim + col] = acc[mi][ni][r];
            }
        }
}

// ---------------------------------------------------------------------------
// Fused attention scores, 128x128 tile, 512 threads = 8 waves (2x4).
// Staging via global_load_lds; u-table OVERLAYS the A/B tiles after the
// K-loop (tiles are dead then) -> LDS 34 KB, 3 blocks/CU target.
// ---------------------------------------------------------------------------
__global__ __launch_bounds__(512, 6) void attn_scores_mfma(
    const short* __restrict__ enc_bf,   // [8192, 1024]
    const short* __restrict__ W1_bf,    // ld 2048, cols [0,1024)
    const float* __restrict__ u4,       // [4][64, 1024]
    const float* __restrict__ attnb,    // [1024]
    const float* __restrict__ vvec,     // [1024]
    float* __restrict__ scores_part)    // [8][8192]
{
    __shared__ short tiles[2][128 * 64];   // As = tiles[0], Bs = tiles[1] (32 KB)
    __shared__ float red[8][64];

    short* As = tiles[0];
    short* Bs = tiles[1];

    const int t = threadIdx.x;
    const int lane = t & 63, wave = t >> 6;     // 8 waves
    const int wr = wave >> 2, wc = wave & 3;    // 2 x 4 wave grid
    const int lr = lane & 15, kh = lane >> 4;
    const int m0 = blockIdx.x * 128;
    const int n0 = blockIdx.y * 128;

    // gload_lds geometry: byte offset o covers row o>>7, short-col (o&127)>>1.
    const int o1 = t * 16;            // 0..8191
    const int o2 = 8192 + t * 16;     // 8192..16383
    const int r1 = o1 >> 7, c1 = (o1 & 127) >> 1;
    const int r2 = o2 >> 7, c2 = (o2 & 127) >> 1;

    f32x4 acc[4][2] = {};

    for (int kg = 0; kg < Hdim; kg += 64) {
        gl_lds16(enc_bf + (size_t)(m0 + r1) * Hdim + kg + c1, As + (o1 >> 1));
        gl_lds16(enc_bf + (size_t)(m0 + r2) * Hdim + kg + c2, As + (o2 >> 1));
        gl_lds16(W1_bf + (size_t)(n0 + r1) * (2 * Hdim) + kg + c1, Bs + (o1 >> 1));
        gl_lds16(W1_bf + (size_t)(n0 + r2) * (2 * Hdim) + kg + c2, Bs + (o2 >> 1));
        __syncthreads();
#pragma unroll
        for (int kk = 0; kk < 64; kk += 32) {
            bf16x8 af[4], bfr[2];
#pragma unroll
            for (int mi = 0; mi < 4; ++mi)
                af[mi] = *(const bf16x8*)(As + (wr * 64 + mi * 16 + lr) * 64 + kk + kh * 8);
#pragma unroll
            for (int ni = 0; ni < 2; ++ni)
                bfr[ni] = *(const bf16x8*)(Bs + (wc * 32 + ni * 16 + lr) * 64 + kk + kh * 8);
#pragma unroll
            for (int mi = 0; mi < 4; ++mi)
#pragma unroll
                for (int ni = 0; ni < 2; ++ni)
                    acc[mi][ni] = __builtin_amdgcn_mfma_f32_16x16x32_bf16(
                        af[mi], bfr[ni], acc[mi][ni], 0, 0, 0);
        }
        __syncthreads();
    }

    // overlay: build u-sum table in the (now dead) tile memory
    float* u_lds = (float*)tiles;         // 64*128 floats = 32 KB
    for (int i = t; i < 64 * 128; i += 512) {
        const int b = i >> 7, hl = i & 127;
        const size_t g = (size_t)b * Hdim + n0 + hl;
        u_lds[i] = u4[g] + u4[65536 + g] + u4[2 * 65536 + g] + u4[3 * 65536 + g]
                 + attnb[n0 + hl];
    }
    __syncthreads();

    float sv[16];
#pragma unroll
    for (int mi = 0; mi < 4; ++mi)
#pragma unroll
        for (int r = 0; r < 4; ++r) {
            const int lrow = mi * 16 + kh * 4 + r;
            const int b = lrow;                 // m0 % 64 == 0
            float s = 0.0f;
#pragma unroll
            for (int ni = 0; ni < 2; ++ni) {
                const int hl = wc * 32 + ni * 16 + lr;
                const float e = fast_tanhf(acc[mi][ni][r] + u_lds[b * 128 + hl]);
                s += e * vvec[n0 + hl];
            }
            sv[mi * 4 + r] = s;
        }
#pragma unroll
    for (int i = 0; i < 16; ++i) {
#pragma unroll
        for (int d = 1; d < 16; d <<= 1)
            sv[i] += __shfl_xor(sv[i], d, 64);
    }
    if (lr == 0) {
#pragma unroll
        for (int mi = 0; mi < 4; ++mi)
#pragma unroll
            for (int r = 0; r < 4; ++r)
                red[wave][mi * 16 + kh * 4 + r] = sv[mi * 4 + r];
    }
    __syncthreads();
    if (t < 128) {
        const int wrr = t >> 6, lrow = t & 63;
        scores_part[(size_t)blockIdx.y * (LSEQ * BSZ) + m0 + t] =
            red[wrr * 4 + 0][lrow] + red[wrr * 4 + 1][lrow] +
            red[wrr * 4 + 2][lrow] + red[wrr * 4 + 3][lrow];
    }
}

// ---------------------------------------------------------------------------
// Fused softmax + weighted context + embedding. grid(64 b, 4 hg), 128 thr.
// ---------------------------------------------------------------------------
__global__ __launch_bounds__(128) void softmax_weighted(
    const float* __restrict__ sp,       // [8][8192]
    const short* __restrict__ enc_bf,   // [8192, 1024]
    const int* __restrict__ ids,
    const float* __restrict__ emb,
    float* __restrict__ attn_out,       // [B, L]
    short* __restrict__ x_bf,           // [64, 2048]
    short* __restrict__ oc_bf)          // [64, 3072]
{
    const int b = blockIdx.x, hg = blockIdx.y, t = threadIdx.x;
    __shared__ float aw[LSEQ];
    __shared__ float red[LSEQ];

    if (hg == 0) {
        const int id = ids[b];
        const int h = t * 8;
        f32x4 e0 = *(const f32x4*)(emb + (size_t)id * Hdim + h);
        f32x4 e1 = *(const f32x4*)(emb + (size_t)id * Hdim + h + 4);
        bf16x8 p;
        p[0] = f2bf(e0[0]); p[1] = f2bf(e0[1]); p[2] = f2bf(e0[2]); p[3] = f2bf(e0[3]);
        p[4] = f2bf(e1[0]); p[5] = f2bf(e1[1]); p[6] = f2bf(e1[2]); p[7] = f2bf(e1[3]);
        *(bf16x8*)(x_bf + (size_t)b * 2048 + h) = p;
        *(bf16x8*)(oc_bf + (size_t)b * 3072 + 2048 + h) = p;
    }

    float s = 0.0f;
#pragma unroll
    for (int g = 0; g < 8; ++g) s += sp[g * (LSEQ * BSZ) + t * 64 + b];
    red[t] = s;
    __syncthreads();
    for (int off = 64; off > 0; off >>= 1) {
        if (t < off) red[t] = fmaxf(red[t], red[t + off]);
        __syncthreads();
    }
    const float mx = red[0];
    __syncthreads();
    const float e = __expf(s - mx);
    red[t] = e;
    __syncthreads();
    for (int off = 64; off > 0; off >>= 1) {
        if (t < off) red[t] += red[t + off];
        __syncthreads();
    }
    const float p = e / red[0];
    aw[t] = p;
    if (hg == 0) attn_out[(size_t)b * LSEQ + t] = p;
    __syncthreads();

    const int h = hg * 256 + t * 2;
    float a0 = 0.0f, a1 = 0.0f;
#pragma unroll 8
    for (int l = 0; l < LSEQ; ++l) {
        const unsigned w = *(const unsigned*)(enc_bf + ((size_t)l * BSZ + b) * Hdim + h);
        const float pw = aw[l];
        a0 = fmaf(pw, __uint_as_float(w << 16), a0);
        a1 = fmaf(pw, __uint_as_float(w & 0xffff0000u), a1);
    }
    const unsigned packed = (unsigned)(unsigned short)f2bf(a0)
                          | ((unsigned)(unsigned short)f2bf(a1) << 16);
    *(unsigned*)(x_bf + (size_t)b * 2048 + 1024 + h) = packed;
    *(unsigned*)(oc_bf + (size_t)b * 3072 + 1024 + h) = packed;
}

// ---------------------------------------------------------------------------
// Streaming skinny GEMM body (512 thr = 8 waves, 64x64 tile, BK=64):
// double-buffered LDS, ONE barrier per k-tile (T3-minimum 2-phase).
// ---------------------------------------------------------------------------
__device__ __forceinline__ void sgemm_body(
    const short* __restrict__ A, int lda,
    const float* __restrict__ B, int ldb,
    const float* __restrict__ bias,
    float* __restrict__ C, int ldc,
    int n0, int kstart, int klen)
{
    __shared__ short As[2][64 * 72];   // 72-pad: 2-way bank alias (free, m136)
    __shared__ short Bs[2][64 * 72];

    const int t = threadIdx.x;               // 0..511
    const int lane = t & 63, wave = t >> 6;  // 8 waves
    const int wm = wave >> 2, wn = wave & 3; // 2 x 4 wave grid
    const int lr = lane & 15, kh = lane >> 4;

    const int sr = t >> 3, sc = (t & 7) * 8; // staging: 64 rows x 64 cols, 8/thread
    const short* Ap = A + (size_t)sr * lda + kstart + sc;
    const float* Bp = B + (size_t)(n0 + sr) * ldb + kstart + sc;

    const int nkt = klen >> 6;

    // prologue: k-tile 0 -> regs -> buf 0
    bf16x8 pa = *(const bf16x8*)(Ap);
    f32x4 pb0 = *(const f32x4*)(Bp);
    f32x4 pb1 = *(const f32x4*)(Bp + 4);
    *(bf16x8*)(&As[0][sr * 72 + sc]) = pa;
    {
        bf16x8 q;
        q[0] = f2bf(pb0[0]); q[1] = f2bf(pb0[1]); q[2] = f2bf(pb0[2]); q[3] = f2bf(pb0[3]);
        q[4] = f2bf(pb1[0]); q[5] = f2bf(pb1[1]); q[6] = f2bf(pb1[2]); q[7] = f2bf(pb1[3]);
        *(bf16x8*)(&Bs[0][sr * 72 + sc]) = q;
    }

    f32x4 acc[2] = {};

    for (int kt = 0; kt < nkt; ++kt) {
        const int cur = kt & 1;
        if (kt + 1 < nkt) {                   // issue next tile's loads
            const int kn = (kt + 1) * 64;
            pa  = *(const bf16x8*)(Ap + kn);
            pb0 = *(const f32x4*)(Bp + kn);
            pb1 = *(const f32x4*)(Bp + kn + 4);
        }
        __syncthreads();                      // buf[cur] ready
#pragma unroll
        for (int kk = 0; kk < 64; kk += 32) {
            bf16x8 af0 = *(const bf16x8*)(&As[cur][(wm * 32 + lr) * 72 + kk + kh * 8]);
            bf16x8 af1 = *(const bf16x8*)(&As[cur][(wm * 32 + 16 + lr) * 72 + kk + kh * 8]);
            bf16x8 bfr = *(const bf16x8*)(&Bs[cur][(wn * 16 + lr) * 72 + kk + kh * 8]);
            acc[0] = __builtin_amdgcn_mfma_f32_16x16x32_bf16(af0, bfr, acc[0], 0, 0, 0);
            acc[1] = __builtin_amdgcn_mfma_f32_16x16x32_bf16(af1, bfr, acc[1], 0, 0, 0);
        }
        if (kt + 1 < nkt) {                   // write regs -> other buffer
            const int nxt = cur ^ 1;
            *(bf16x8*)(&As[nxt][sr * 72 + sc]) = pa;
            bf16x8 q;
            q[0] = f2bf(pb0[0]); q[1] = f2bf(pb0[1]); q[2] = f2bf(pb0[2]); q[3] = f2bf(pb0[3]);
            q[4] = f2bf(pb1[0]); q[5] = f2bf(pb1[1]); q[6] = f2bf(pb1[2]); q[7] = f2bf(pb1[3]);
            *(bf16x8*)(&Bs[nxt][sr * 72 + sc]) = q;
        }
    }

    const int col = n0 + wn * 16 + lr;
    const float bb = bias ? bias[col] : 0.0f;
#pragma unroll
    for (int mi = 0; mi < 2; ++mi)
#pragma unroll
        for (int r = 0; r < 4; ++r) {
            const int row = wm * 32 + mi * 16 + kh * 4 + r;
            C[(size_t)row * ldc + col] = acc[mi][r] + bb;
        }
}

// Output projection: logits = oc_bf @ out_W^T + out_b. grid(500), 512 thr.
__global__ __launch_bounds__(512) void outproj_stream(
    const short* __restrict__ A, const float* __restrict__ B,
    const float* __restrict__ bias, float* __restrict__ logits)
{
    sgemm_body(A, 3 * Hdim, B, 3 * Hdim, bias, logits, VOC,
               blockIdx.x * 64, 0, 3 * Hdim);
}

// Merged GRU gate GEMMs, split-K x4 partials. grid(96, 4), 512 thr.
__global__ __launch_bounds__(512) void gxgh_stream(
    const short* __restrict__ x_bf, const float* __restrict__ w_ih,
    const short* __restrict__ hidden_bf, const float* __restrict__ w_hh,
    float* __restrict__ gx4, float* __restrict__ gh4)
{
    const size_t P = (size_t)BSZ * 3 * Hdim;
    if (blockIdx.x < 48)
        sgemm_body(x_bf, 2 * Hdim, w_ih, 2 * Hdim, nullptr,
                   gx4 + blockIdx.y * P, 3 * Hdim,
                   blockIdx.x * 64, blockIdx.y * 512, 512);
    else
        sgemm_body(hidden_bf, Hdim, w_hh, Hdim, nullptr,
                   gh4 + blockIdx.y * P, 3 * Hdim,
                   (blockIdx.x - 48) * 64, blockIdx.y * 256, 256);
}

// ---------------------------------------------------------------------------
// GRU elementwise; sums 4 split-K partials + biases; bf16 out_cat write.
// ---------------------------------------------------------------------------
__global__ __launch_bounds__(256) void gru_kernel(
    const float* __restrict__ gx4, const float* __restrict__ gh4,
    const float* __restrict__ b_ih, const float* __restrict__ b_hh,
    const float* __restrict__ h0,
    float* __restrict__ hnew_out, short* __restrict__ oc_bf)
{
    const int idx = blockIdx.x * 256 + threadIdx.x;
    const int b = idx >> 10, h = idx & 1023;
    const size_t g3 = (size_t)b * (3 * Hdim);
    const size_t P = (size_t)BSZ * 3 * Hdim;
    float xr = b_ih[h], xz = b_ih[Hdim + h], xn = b_ih[2 * Hdim + h];
    float hr = b_hh[h], hz = b_hh[Hdim + h], hn = b_hh[2 * Hdim + h];
#pragma unroll
    for (int s = 0; s < 4; ++s) {
        xr += gx4[s * P + g3 + h];
        xz += gx4[s * P + g3 + Hdim + h];
        xn += gx4[s * P + g3 + 2 * Hdim + h];
        hr += gh4[s * P + g3 + h];
        hz += gh4[s * P + g3 + Hdim + h];
        hn += gh4[s * P + g3 + 2 * Hdim + h];
    }
    const float r = sigmoidf(xr + hr);
    const float z = sigmoidf(xz + hz);
    const float n = fast_tanhf(xn + r * hn);
    const float hv = (1.0f - z) * n + z * h0[(size_t)b * Hdim + h];
    hnew_out[(size_t)b * Hdim + h] = hv;
    oc_bf[g3 + h] = f2bf(hv);
}

// ---------------------------------------------------------------------------
extern "C" void kernel_launch(void* const* d_in, const int* in_sizes, int n_in,
                              void* d_out, int out_size, void* d_ws, size_t ws_size,
                              hipStream_t stream)
{
    const int*   ids    = (const int*)d_in[0];
    const float* hidden = (const float*)d_in[1];
    const float* enc    = (const float*)d_in[2];
    const float* emb    = (const float*)d_in[3];
    const float* attnW  = (const float*)d_in[4];
    const float* attnb  = (const float*)d_in[5];
    const float* vvec   = (const float*)d_in[6];
    const float* w_ih   = (const float*)d_in[7];
    const float* w_hh   = (const float*)d_in[8];
    const float* b_ih   = (const float*)d_in[9];
    const float* b_hh   = (const float*)d_in[10];
    const float* out_W  = (const float*)d_in[11];
    const float* out_b  = (const float*)d_in[12];

    float* out        = (float*)d_out;
    float* out_logits = out;
    float* out_hnew   = out + (size_t)BSZ * VOC;
    float* out_attn   = out_hnew + (size_t)BSZ * Hdim;

    float* ws = (float*)d_ws;
    short* enc_bf    = (short*)ws;
    short* attnW_bf  = (short*)(ws + 4194304);
    short* hidden_bf = (short*)(ws + 5242880);
    float* ws_u4  = ws + 5275648;
    float* ws_sp  = ws_u4 + 262144;
    short* x_bf   = (short*)(ws_sp + 65536);
    short* oc_bf  = (short*)(ws_sp + 131072);
    float* ws_gx4 = ws_sp + 229376;
    float* ws_gh4 = ws_gx4 + 786432;

    // 1. f32 -> bf16 one-pass conversion
    convert_bf16<<<dim3(1024), 256, 0, stream>>>(
        enc, attnW, hidden, enc_bf, attnW_bf, hidden_bf);

    // 2. u partials: hidden_bf @ W2_bf^T (split-K x4, 32 blocks)
    ugemm<<<dim3(Hdim / 128, 4), 256, 0, stream>>>(
        hidden_bf, attnW_bf + Hdim, ws_u4);

    // 3. fused energy GEMM + u-combine + tanh + v-reduction (gload_lds)
    attn_scores_mfma<<<dim3(LSEQ / 2, 8), 512, 0, stream>>>(
        enc_bf, attnW_bf, ws_u4, attnb, vvec, ws_sp);

    // 4. softmax + weighted context + embedding (256 blocks)
    softmax_weighted<<<dim3(BSZ, 4), 128, 0, stream>>>(
        ws_sp, enc_bf, ids, emb, out_attn, x_bf, oc_bf);

    // 5. merged GRU gate GEMMs, double-buffered streaming (384 blocks)
    gxgh_stream<<<dim3(96, 4), 512, 0, stream>>>(
        x_bf, w_ih, hidden_bf, w_hh, ws_gx4, ws_gh4);

    // 6. GRU elementwise
    gru_kernel<<<dim3(BSZ * Hdim / 256), 256, 0, stream>>>(
        ws_gx4, ws_gh4, b_ih, b_hh, hidden, out_hnew, oc_bf);

    // 7. output projection, double-buffered streaming (500 blocks)
    outproj_stream<<<dim3(VOC / 64), 512, 0, stream>>>(
        oc_bf, out_W, out_b, out_logits);
}